// Round 1
// baseline (1806.103 us; speedup 1.0000x reference)
//
#include <hip/hip_runtime.h>
#include <stdint.h>

typedef unsigned short u16;
typedef short bf16x8 __attribute__((ext_vector_type(8)));
typedef float f32x4 __attribute__((ext_vector_type(4)));

#define TOKENS 8192
#define SEQ 2048
#define DM 1024
#define DI 2048

__device__ __forceinline__ float bf2f(u16 u) {
  union { uint32_t i; float f; } v; v.i = ((uint32_t)u) << 16; return v.f;
}
__device__ __forceinline__ u16 f2bf(float f) {
  union { float f; uint32_t i; } v; v.f = f;
  uint32_t r = v.i + 0x7FFFu + ((v.i >> 16) & 1u);
  return (u16)(r >> 16);
}

__device__ __forceinline__ void g2lds16(const void* g, void* l) {
  __builtin_amdgcn_global_load_lds(
      (const __attribute__((address_space(1))) uint32_t*)g,
      (__attribute__((address_space(3))) uint32_t*)l, 16, 0, 0);
}

// ---------------- transpose fp32 [R][C] -> bf16 [C][R] ----------------
__global__ __launch_bounds__(256)
void transpose_to_bf16(const float* __restrict__ src, u16* __restrict__ dst,
                       int R, int C) {
  __shared__ float tile[64][65];
  const int i = threadIdx.x;
  const int tilesC = C >> 6;
  const int br = blockIdx.x / tilesC, bc = blockIdx.x % tilesC;
  const int r0 = br << 6, c0 = bc << 6;
  const int cx = (i & 15) << 2, ry = i >> 4;
#pragma unroll
  for (int p = 0; p < 4; ++p) {
    int row = ry + p * 16;
    float4 v = *(const float4*)&src[(size_t)(r0 + row) * C + c0 + cx];
    tile[row][cx + 0] = v.x; tile[row][cx + 1] = v.y;
    tile[row][cx + 2] = v.z; tile[row][cx + 3] = v.w;
  }
  __syncthreads();
#pragma unroll
  for (int p = 0; p < 4; ++p) {
    int cr = ry + p * 16;  // output row = source col c0+cr
    ushort4 o;
    o.x = f2bf(tile[cx + 0][cr]); o.y = f2bf(tile[cx + 1][cr]);
    o.z = f2bf(tile[cx + 2][cr]); o.w = f2bf(tile[cx + 3][cr]);
    *(ushort4*)&dst[(size_t)(c0 + cr) * R + r0 + cx] = o;
  }
}

// ---------------- layernorm fp32 -> bf16 ----------------
__global__ __launch_bounds__(256)
void layernorm_bf16(const float* __restrict__ x, const float* __restrict__ lw,
                    const float* __restrict__ lb, u16* __restrict__ xn) {
  const int row = blockIdx.x, tid = threadIdx.x;
  const float4 v = *(const float4*)&x[(size_t)row * DM + tid * 4];
  float s = v.x + v.y + v.z + v.w;
  float q = v.x * v.x + v.y * v.y + v.z * v.z + v.w * v.w;
#pragma unroll
  for (int m = 1; m < 64; m <<= 1) { s += __shfl_xor(s, m); q += __shfl_xor(q, m); }
  __shared__ float red[8];
  const int w = tid >> 6, lane = tid & 63;
  if (lane == 0) { red[w] = s; red[4 + w] = q; }
  __syncthreads();
  s = red[0] + red[1] + red[2] + red[3];
  q = red[4] + red[5] + red[6] + red[7];
  const float mu = s * (1.f / DM);
  const float var = q * (1.f / DM) - mu * mu;
  const float rs = rsqrtf(var + 1e-5f);
  const float4 wv = *(const float4*)&lw[tid * 4];
  const float4 bv = *(const float4*)&lb[tid * 4];
  ushort4 o;
  o.x = f2bf((v.x - mu) * rs * wv.x + bv.x);
  o.y = f2bf((v.y - mu) * rs * wv.y + bv.y);
  o.z = f2bf((v.z - mu) * rs * wv.z + bv.z);
  o.w = f2bf((v.w - mu) * rs * wv.w + bv.w);
  *(ushort4*)&xn[(size_t)row * DM + tid * 4] = o;
}

// ---------------- bf16 MFMA GEMM: C = A[M][K] * Bt[N][K]^T + bias ----------------
// EPI 0: out bf16.  EPI 1: out fp32 = acc + bias + resid.
template <int EPI>
__global__ __launch_bounds__(256)
void gemm_bt(const u16* __restrict__ A, const u16* __restrict__ Bt,
             const float* __restrict__ bias, const float* __restrict__ resid,
             void* __restrict__ out, int M, int N, int K) {
  __shared__ __align__(16) u16 As[128 * 64];
  __shared__ __align__(16) u16 Bs[128 * 64];
  const int tid = threadIdx.x, w = tid >> 6, lane = tid & 63;
  const int ntiles = N >> 7;
  const int tm = blockIdx.x / ntiles, tn = blockIdx.x % ntiles;
  const int m0 = tm << 7, n0 = tn << 7;
  f32x4 acc[4][4];
#pragma unroll
  for (int mi = 0; mi < 4; ++mi)
#pragma unroll
    for (int ni = 0; ni < 4; ++ni) acc[mi][ni] = (f32x4){0.f, 0.f, 0.f, 0.f};

  const int chunkbase = w * 64 + lane;
  const int wm = (w >> 1) * 64, wn = (w & 1) * 64;
  const int fr = lane & 15, fg = lane >> 4;

  for (int kt = 0; kt < K; kt += 64) {
#pragma unroll
    for (int i = 0; i < 4; ++i) {
      int ch = chunkbase + i * 256;
      int row = ch >> 3, c16 = ch & 7;
      g2lds16(A + (size_t)(m0 + row) * K + kt + c16 * 8,
              (u16*)As + (size_t)(w * 64 + i * 256) * 8);
      g2lds16(Bt + (size_t)(n0 + row) * K + kt + c16 * 8,
              (u16*)Bs + (size_t)(w * 64 + i * 256) * 8);
    }
    __syncthreads();
#pragma unroll
    for (int ks = 0; ks < 2; ++ks) {
      bf16x8 af[4], bfr[4];
#pragma unroll
      for (int mi = 0; mi < 4; ++mi)
        af[mi] = *(const bf16x8*)&As[(wm + mi * 16 + fr) * 64 + ks * 32 + fg * 8];
#pragma unroll
      for (int ni = 0; ni < 4; ++ni)
        bfr[ni] = *(const bf16x8*)&Bs[(wn + ni * 16 + fr) * 64 + ks * 32 + fg * 8];
#pragma unroll
      for (int mi = 0; mi < 4; ++mi)
#pragma unroll
        for (int ni = 0; ni < 4; ++ni)
          acc[mi][ni] = __builtin_amdgcn_mfma_f32_16x16x32_bf16(
              af[mi], bfr[ni], acc[mi][ni], 0, 0, 0);
    }
    __syncthreads();
  }
#pragma unroll
  for (int mi = 0; mi < 4; ++mi)
#pragma unroll
    for (int ni = 0; ni < 4; ++ni) {
      const int col = n0 + wn + ni * 16 + fr;
      const float bcol = bias[col];
#pragma unroll
      for (int j = 0; j < 4; ++j) {
        const int row = m0 + wm + mi * 16 + fg * 4 + j;
        float v = acc[mi][ni][j] + bcol;
        if (EPI == 1) {
          ((float*)out)[(size_t)row * N + col] = v + resid[(size_t)row * N + col];
        } else {
          ((u16*)out)[(size_t)row * N + col] = f2bf(v);
        }
      }
    }
}

// ---------------- fused causal conv1d + SiLU + ssm projection ----------------
// one block per token: x_conv row (bf16 out + LDS fp32), then BC = row @ W_x + b_x
__global__ __launch_bounds__(256)
void conv_bc(const u16* __restrict__ xg, const float* __restrict__ cw,
             const float* __restrict__ cb, const float* __restrict__ wx,
             const float* __restrict__ bx, u16* __restrict__ xconv,
             float* __restrict__ BC) {
  __shared__ float rowf[DI];
  __shared__ float part[8][32];
  const int t = blockIdx.x, tid = threadIdx.x;
  const int s = t & (SEQ - 1);
  const int d = tid * 8;
  float xv[4][8];
#pragma unroll
  for (int j = 0; j < 4; ++j) {
    const int ss = s - 3 + j;
    if (ss >= 0) {
      uint4 u = *(const uint4*)&xg[(size_t)(t - 3 + j) * (2 * DI) + d];
      const u16* pu = (const u16*)&u;
#pragma unroll
      for (int q = 0; q < 8; ++q) xv[j][q] = bf2f(pu[q]);
    } else {
#pragma unroll
      for (int q = 0; q < 8; ++q) xv[j][q] = 0.f;
    }
  }
  u16 outp[8];
#pragma unroll
  for (int q = 0; q < 8; ++q) {
    const float4 wq = *(const float4*)&cw[(d + q) * 4];
    float a = cb[d + q] + wq.x * xv[0][q] + wq.y * xv[1][q] + wq.z * xv[2][q] +
              wq.w * xv[3][q];
    float sl = a / (1.f + __expf(-a));
    rowf[d + q] = sl;
    outp[q] = f2bf(sl);
  }
  *(uint4*)&xconv[(size_t)t * DI + d] = *(const uint4*)outp;
  __syncthreads();
  const int n = tid & 31, p = tid >> 5;
  float acc = 0.f;
  const int k0 = p * 256;
#pragma unroll 8
  for (int k = 0; k < 256; ++k)
    acc = fmaf(rowf[k0 + k], wx[(size_t)(k0 + k) * 32 + n], acc);
  part[p][n] = acc;
  __syncthreads();
  if (tid < 32) {
    float sum = bx[tid];
#pragma unroll
    for (int pp = 0; pp < 8; ++pp) sum += part[pp][tid];
    // interleave: B -> 2n, C -> 2n+1 so the scan reads a float2 per lane
    BC[(size_t)t * 32 + ((tid & 15) * 2 + (tid >> 4))] = sum;
  }
}

// ---------------- selective scan (16 lanes per (b,d) chain) ----------------
__global__ __launch_bounds__(256)
void scan_kernel(const u16* __restrict__ xconv, const u16* __restrict__ xg,
                 const float* __restrict__ BC, const float* __restrict__ A_log,
                 const float* __restrict__ Dv, u16* __restrict__ yact) {
  __shared__ u16 buf[64 * 16];
  const int blk = blockIdx.x;      // 512 blocks: 4 batches * 128
  const int batch = blk >> 7;
  const int d0 = (blk & 127) << 4;
  const int tid = threadIdx.x, w = tid >> 6, lane = tid & 63;
  const int c = (w << 2) + (lane >> 4);  // chain 0..15 within block
  const int n = lane & 15;               // state
  const int dch = d0 + c;
  const float dA = __expf(-__expf(A_log[dch * 16 + n]));
  const float Dd = Dv[dch];
  const u16* xcp = xconv + (size_t)batch * SEQ * DI + dch;
  const u16* gp = xg + (size_t)batch * SEQ * (2 * DI) + DI + dch;
  const float* bcp = BC + (size_t)batch * SEQ * 32 + 2 * n;
  float h = 0.f;
  for (int t = 0; t < SEQ; ++t) {
    const float xc = bf2f(*xcp);
    const float2 bc = *(const float2*)bcp;
    const float g = bf2f(*gp);
    h = fmaf(dA, h, xc * bc.x);
    float pp = h * bc.y;
    pp += __shfl_xor(pp, 1); pp += __shfl_xor(pp, 2);
    pp += __shfl_xor(pp, 4); pp += __shfl_xor(pp, 8);
    const float ya = (pp + xc * Dd) * (g / (1.f + __expf(-g)));
    if (n == 0) buf[(t & 63) * 16 + c] = f2bf(ya);
    xcp += DI; gp += 2 * DI; bcp += 32;
    if ((t & 63) == 63) {
      __syncthreads();
      const int tb = t - 63;
      for (int e = tid; e < 1024; e += 256)
        yact[(size_t)(batch * SEQ + tb + (e >> 4)) * DI + d0 + (e & 15)] = buf[e];
      __syncthreads();
    }
  }
}

extern "C" void kernel_launch(void* const* d_in, const int* in_sizes, int n_in,
                              void* d_out, int out_size, void* d_ws, size_t ws_size,
                              hipStream_t stream) {
  const float* x     = (const float*)d_in[0];
  const float* ln_w  = (const float*)d_in[1];
  const float* ln_b  = (const float*)d_in[2];
  const float* W_in  = (const float*)d_in[3];
  const float* b_in  = (const float*)d_in[4];
  const float* cw    = (const float*)d_in[5];
  const float* cb    = (const float*)d_in[6];
  const float* A_log = (const float*)d_in[7];
  const float* Dv    = (const float*)d_in[8];
  const float* W_x   = (const float*)d_in[9];
  const float* b_x   = (const float*)d_in[10];
  const float* W_out = (const float*)d_in[11];
  const float* b_out = (const float*)d_in[12];

  char* ws = (char*)d_ws;
  size_t off = 0;
  auto alloc = [&](size_t bytes) {
    void* p = ws + off;
    off += (bytes + 255) & ~(size_t)255;
    return p;
  };
  u16* WinT  = (u16*)alloc((size_t)(2 * DI) * DM * 2);   // [4096][1024] bf16
  u16* WoutT = (u16*)alloc((size_t)DM * DI * 2);          // [1024][2048] bf16
  u16* xn    = (u16*)alloc((size_t)TOKENS * DM * 2);
  u16* xg    = (u16*)alloc((size_t)TOKENS * (2 * DI) * 2);
  u16* xconv = (u16*)alloc((size_t)TOKENS * DI * 2);
  float* BC  = (float*)alloc((size_t)TOKENS * 32 * 4);
  u16* yact  = (u16*)alloc((size_t)TOKENS * DI * 2);
  (void)ws_size; (void)in_sizes; (void)n_in; (void)out_size;

  transpose_to_bf16<<<(DM / 64) * ((2 * DI) / 64), 256, 0, stream>>>(W_in, WinT, DM, 2 * DI);
  transpose_to_bf16<<<(DI / 64) * (DM / 64), 256, 0, stream>>>(W_out, WoutT, DI, DM);
  layernorm_bf16<<<TOKENS, 256, 0, stream>>>(x, ln_w, ln_b, xn);
  gemm_bt<0><<<(TOKENS / 128) * ((2 * DI) / 128), 256, 0, stream>>>(
      xn, WinT, b_in, nullptr, xg, TOKENS, 2 * DI, DM);
  conv_bc<<<TOKENS, 256, 0, stream>>>(xg, cw, cb, W_x, b_x, xconv, BC);
  scan_kernel<<<512, 256, 0, stream>>>(xconv, xg, BC, A_log, Dv, yact);
  gemm_bt<1><<<(TOKENS / 128) * (DM / 128), 256, 0, stream>>>(
      yact, WoutT, b_out, x, d_out, TOKENS, DM, DI);
}

// Round 3
// 483.136 us; speedup vs baseline: 3.7383x; 3.7383x over previous
//
#include <hip/hip_runtime.h>
#include <stdint.h>

typedef unsigned short u16;
typedef short bf16x8 __attribute__((ext_vector_type(8)));
typedef float f32x4 __attribute__((ext_vector_type(4)));

#define TOKENS 8192
#define SEQ 2048
#define DM 1024
#define DI 2048
#define NCH 32   // time chunks per sequence
#define CLEN 64  // SEQ / NCH

__device__ __forceinline__ float bf2f(u16 u) {
  union { uint32_t i; float f; } v; v.i = ((uint32_t)u) << 16; return v.f;
}
__device__ __forceinline__ u16 f2bf(float f) {
  union { float f; uint32_t i; } v; v.f = f;
  uint32_t r = v.i + 0x7FFFu + ((v.i >> 16) & 1u);
  return (u16)(r >> 16);
}

__device__ __forceinline__ void g2lds16(const void* g, void* l) {
  __builtin_amdgcn_global_load_lds(
      (const __attribute__((address_space(1))) uint32_t*)g,
      (__attribute__((address_space(3))) uint32_t*)l, 16, 0, 0);
}

// ---------------- transpose fp32 [R][C] -> bf16 [C][R] ----------------
__global__ __launch_bounds__(256)
void transpose_to_bf16(const float* __restrict__ src, u16* __restrict__ dst,
                       int R, int C) {
  __shared__ float tile[64][65];
  const int i = threadIdx.x;
  const int tilesC = C >> 6;
  const int br = blockIdx.x / tilesC, bc = blockIdx.x % tilesC;
  const int r0 = br << 6, c0 = bc << 6;
  const int cx = (i & 15) << 2, ry = i >> 4;
#pragma unroll
  for (int p = 0; p < 4; ++p) {
    int row = ry + p * 16;
    float4 v = *(const float4*)&src[(size_t)(r0 + row) * C + c0 + cx];
    tile[row][cx + 0] = v.x; tile[row][cx + 1] = v.y;
    tile[row][cx + 2] = v.z; tile[row][cx + 3] = v.w;
  }
  __syncthreads();
#pragma unroll
  for (int p = 0; p < 4; ++p) {
    int cr = ry + p * 16;  // output row = source col c0+cr
    ushort4 o;
    o.x = f2bf(tile[cx + 0][cr]); o.y = f2bf(tile[cx + 1][cr]);
    o.z = f2bf(tile[cx + 2][cr]); o.w = f2bf(tile[cx + 3][cr]);
    *(ushort4*)&dst[(size_t)(c0 + cr) * R + r0 + cx] = o;
  }
}

// ---------------- layernorm fp32 -> bf16 ----------------
__global__ __launch_bounds__(256)
void layernorm_bf16(const float* __restrict__ x, const float* __restrict__ lw,
                    const float* __restrict__ lb, u16* __restrict__ xn) {
  const int row = blockIdx.x, tid = threadIdx.x;
  const float4 v = *(const float4*)&x[(size_t)row * DM + tid * 4];
  float s = v.x + v.y + v.z + v.w;
  float q = v.x * v.x + v.y * v.y + v.z * v.z + v.w * v.w;
#pragma unroll
  for (int m = 1; m < 64; m <<= 1) { s += __shfl_xor(s, m); q += __shfl_xor(q, m); }
  __shared__ float red[8];
  const int w = tid >> 6, lane = tid & 63;
  if (lane == 0) { red[w] = s; red[4 + w] = q; }
  __syncthreads();
  s = red[0] + red[1] + red[2] + red[3];
  q = red[4] + red[5] + red[6] + red[7];
  const float mu = s * (1.f / DM);
  const float var = q * (1.f / DM) - mu * mu;
  const float rs = rsqrtf(var + 1e-5f);
  const float4 wv = *(const float4*)&lw[tid * 4];
  const float4 bv = *(const float4*)&lb[tid * 4];
  ushort4 o;
  o.x = f2bf((v.x - mu) * rs * wv.x + bv.x);
  o.y = f2bf((v.y - mu) * rs * wv.y + bv.y);
  o.z = f2bf((v.z - mu) * rs * wv.z + bv.z);
  o.w = f2bf((v.w - mu) * rs * wv.w + bv.w);
  *(ushort4*)&xn[(size_t)row * DM + tid * 4] = o;
}

// ---------------- bf16 MFMA GEMM: C = A[M][K] * Bt[N][K]^T + bias ----------------
template <int EPI>
__global__ __launch_bounds__(256)
void gemm_bt(const u16* __restrict__ A, const u16* __restrict__ Bt,
             const float* __restrict__ bias, const float* __restrict__ resid,
             void* __restrict__ out, int M, int N, int K) {
  __shared__ __align__(16) u16 As[128 * 64];
  __shared__ __align__(16) u16 Bs[128 * 64];
  const int tid = threadIdx.x, w = tid >> 6, lane = tid & 63;
  const int ntiles = N >> 7;
  const int tm = blockIdx.x / ntiles, tn = blockIdx.x % ntiles;
  const int m0 = tm << 7, n0 = tn << 7;
  f32x4 acc[4][4];
#pragma unroll
  for (int mi = 0; mi < 4; ++mi)
#pragma unroll
    for (int ni = 0; ni < 4; ++ni) acc[mi][ni] = (f32x4){0.f, 0.f, 0.f, 0.f};

  const int chunkbase = w * 64 + lane;
  const int wm = (w >> 1) * 64, wn = (w & 1) * 64;
  const int fr = lane & 15, fg = lane >> 4;

  for (int kt = 0; kt < K; kt += 64) {
#pragma unroll
    for (int i = 0; i < 4; ++i) {
      int ch = chunkbase + i * 256;
      int row = ch >> 3, c16 = ch & 7;
      g2lds16(A + (size_t)(m0 + row) * K + kt + c16 * 8,
              (u16*)As + (size_t)(w * 64 + i * 256) * 8);
      g2lds16(Bt + (size_t)(n0 + row) * K + kt + c16 * 8,
              (u16*)Bs + (size_t)(w * 64 + i * 256) * 8);
    }
    __syncthreads();
#pragma unroll
    for (int ks = 0; ks < 2; ++ks) {
      bf16x8 af[4], bfr[4];
#pragma unroll
      for (int mi = 0; mi < 4; ++mi)
        af[mi] = *(const bf16x8*)&As[(wm + mi * 16 + fr) * 64 + ks * 32 + fg * 8];
#pragma unroll
      for (int ni = 0; ni < 4; ++ni)
        bfr[ni] = *(const bf16x8*)&Bs[(wn + ni * 16 + fr) * 64 + ks * 32 + fg * 8];
#pragma unroll
      for (int mi = 0; mi < 4; ++mi)
#pragma unroll
        for (int ni = 0; ni < 4; ++ni)
          acc[mi][ni] = __builtin_amdgcn_mfma_f32_16x16x32_bf16(
              af[mi], bfr[ni], acc[mi][ni], 0, 0, 0);
    }
    __syncthreads();
  }
#pragma unroll
  for (int mi = 0; mi < 4; ++mi)
#pragma unroll
    for (int ni = 0; ni < 4; ++ni) {
      const int col = n0 + wn + ni * 16 + fr;
      const float bcol = bias[col];
#pragma unroll
      for (int j = 0; j < 4; ++j) {
        const int row = m0 + wm + mi * 16 + fg * 4 + j;
        float v = acc[mi][ni][j] + bcol;
        if (EPI == 1) {
          ((float*)out)[(size_t)row * N + col] = v + resid[(size_t)row * N + col];
        } else {
          ((u16*)out)[(size_t)row * N + col] = f2bf(v);
        }
      }
    }
}

// ---------------- fused causal conv1d + SiLU + ssm projection ----------------
__global__ __launch_bounds__(256)
void conv_bc(const u16* __restrict__ xg, const float* __restrict__ cw,
             const float* __restrict__ cb, const float* __restrict__ wx,
             const float* __restrict__ bx, u16* __restrict__ xconv,
             float* __restrict__ BC) {
  __shared__ float rowf[DI];
  __shared__ float part[8][32];
  const int t = blockIdx.x, tid = threadIdx.x;
  const int s = t & (SEQ - 1);
  const int d = tid * 8;
  float xv[4][8];
#pragma unroll
  for (int j = 0; j < 4; ++j) {
    const int ss = s - 3 + j;
    if (ss >= 0) {
      uint4 u = *(const uint4*)&xg[(size_t)(t - 3 + j) * (2 * DI) + d];
      const u16* pu = (const u16*)&u;
#pragma unroll
      for (int q = 0; q < 8; ++q) xv[j][q] = bf2f(pu[q]);
    } else {
#pragma unroll
      for (int q = 0; q < 8; ++q) xv[j][q] = 0.f;
    }
  }
  u16 outp[8];
#pragma unroll
  for (int q = 0; q < 8; ++q) {
    const float4 wq = *(const float4*)&cw[(d + q) * 4];
    float a = cb[d + q] + wq.x * xv[0][q] + wq.y * xv[1][q] + wq.z * xv[2][q] +
              wq.w * xv[3][q];
    float sl = a / (1.f + __expf(-a));
    rowf[d + q] = sl;
    outp[q] = f2bf(sl);
  }
  *(uint4*)&xconv[(size_t)t * DI + d] = *(const uint4*)outp;
  __syncthreads();
  const int n = tid & 31, p = tid >> 5;
  float acc = 0.f;
  const int k0 = p * 256;
#pragma unroll 8
  for (int k = 0; k < 256; ++k)
    acc = fmaf(rowf[k0 + k], wx[(size_t)(k0 + k) * 32 + n], acc);
  part[p][n] = acc;
  __syncthreads();
  if (tid < 32) {
    float sum = bx[tid];
#pragma unroll
    for (int pp = 0; pp < 8; ++pp) sum += part[pp][tid];
    // interleave: B -> 2n, C -> 2n+1 so scan passes read pairs
    BC[(size_t)t * 32 + ((tid & 15) * 2 + (tid >> 4))] = sum;
  }
}

// ---------------- chunked selective scan ----------------
// Pass A: per (b, chunk, d) local recurrence with h0=0; store chunk-final state.
__global__ __launch_bounds__(256)
void scan_passA(const u16* __restrict__ xconv, const float* __restrict__ BC,
                const float* __restrict__ A_log, float* __restrict__ F) {
  __shared__ float bcs[CLEN * 32];
  const int blk = blockIdx.x;  // [b:2][dg:3][j:5]
  const int j = blk & (NCH - 1);
  const int dg = (blk >> 5) & 7;
  const int b = blk >> 8;
  const int tid = threadIdx.x;
  const int d = dg * 256 + tid;
  const int t0 = j * CLEN;
  {
    const float4* s4 = (const float4*)(BC + (size_t)(b * SEQ + t0) * 32);
    float4* d4 = (float4*)bcs;
#pragma unroll
    for (int i = 0; i < 2; ++i) d4[tid + i * 256] = s4[tid + i * 256];
  }
  float dA[16], h[16];
#pragma unroll
  for (int n = 0; n < 16; ++n) {
    dA[n] = __expf(-__expf(A_log[d * 16 + n]));
    h[n] = 0.f;
  }
  __syncthreads();
  const u16* xcp = xconv + (size_t)(b * SEQ + t0) * DI + d;
  for (int t = 0; t < CLEN; ++t) {
    const float xc = bf2f(*xcp);
    xcp += DI;
#pragma unroll
    for (int n = 0; n < 16; ++n)
      h[n] = fmaf(dA[n], h[n], xc * bcs[t * 32 + 2 * n]);
  }
  float* fp = F + ((size_t)((b * NCH + j) * DI) + d) * 16;
#pragma unroll
  for (int n = 0; n < 16; n += 4) {
    float4 v = {h[n], h[n + 1], h[n + 2], h[n + 3]};
    *(float4*)&fp[n] = v;
  }
}

// Pass B: per (b,d,n): sequential scan over the 32 chunk finals -> carry-in states (in place).
__global__ __launch_bounds__(256)
void scan_passB(const float* __restrict__ A_log, float* __restrict__ F) {
  const int gid = blockIdx.x * 256 + threadIdx.x;  // (b, d, n)
  const int n = gid & 15;
  const int d = (gid >> 4) & (DI - 1);
  const int b = gid >> 15;
  const float dAL = __expf(-(float)CLEN * __expf(A_log[d * 16 + n]));
  float carry = 0.f;
  const size_t base = ((size_t)(b * NCH) * DI + d) * 16 + n;
  const size_t stride = (size_t)DI * 16;
  for (int j = 0; j < NCH; ++j) {
    const size_t idx = base + (size_t)j * stride;
    const float f = F[idx];
    F[idx] = carry;
    carry = fmaf(dAL, carry, f);
  }
}

// Pass C: re-run recurrence seeded with carry-in; fuse C-dot, +x*D, *silu(gate), bf16 store.
__global__ __launch_bounds__(256)
void scan_passC(const u16* __restrict__ xconv, const u16* __restrict__ xg,
                const float* __restrict__ BC, const float* __restrict__ A_log,
                const float* __restrict__ Dv, const float* __restrict__ F,
                u16* __restrict__ yact) {
  __shared__ float bcs[CLEN * 32];
  const int blk = blockIdx.x;
  const int j = blk & (NCH - 1);
  const int dg = (blk >> 5) & 7;
  const int b = blk >> 8;
  const int tid = threadIdx.x;
  const int d = dg * 256 + tid;
  const int t0 = j * CLEN;
  {
    const float4* s4 = (const float4*)(BC + (size_t)(b * SEQ + t0) * 32);
    float4* d4 = (float4*)bcs;
#pragma unroll
    for (int i = 0; i < 2; ++i) d4[tid + i * 256] = s4[tid + i * 256];
  }
  float dA[16], h[16];
  const float* fp = F + ((size_t)((b * NCH + j) * DI) + d) * 16;
#pragma unroll
  for (int n = 0; n < 16; n += 4) {
    float4 v = *(const float4*)&fp[n];
    h[n] = v.x; h[n + 1] = v.y; h[n + 2] = v.z; h[n + 3] = v.w;
  }
#pragma unroll
  for (int n = 0; n < 16; ++n) dA[n] = __expf(-__expf(A_log[d * 16 + n]));
  const float Dd = Dv[d];
  __syncthreads();
  const u16* xcp = xconv + (size_t)(b * SEQ + t0) * DI + d;
  const u16* gp = xg + (size_t)(b * SEQ + t0) * (2 * DI) + DI + d;
  u16* yp = yact + (size_t)(b * SEQ + t0) * DI + d;
  for (int t = 0; t < CLEN; ++t) {
    const float xc = bf2f(*xcp);
    const float g = bf2f(*gp);
    float y0 = 0.f, y1 = 0.f, y2 = 0.f, y3 = 0.f;
#pragma unroll
    for (int n = 0; n < 16; n += 4) {
      h[n]     = fmaf(dA[n],     h[n],     xc * bcs[t * 32 + 2 * n]);
      y0 = fmaf(bcs[t * 32 + 2 * n + 1], h[n], y0);
      h[n + 1] = fmaf(dA[n + 1], h[n + 1], xc * bcs[t * 32 + 2 * n + 2]);
      y1 = fmaf(bcs[t * 32 + 2 * n + 3], h[n + 1], y1);
      h[n + 2] = fmaf(dA[n + 2], h[n + 2], xc * bcs[t * 32 + 2 * n + 4]);
      y2 = fmaf(bcs[t * 32 + 2 * n + 5], h[n + 2], y2);
      h[n + 3] = fmaf(dA[n + 3], h[n + 3], xc * bcs[t * 32 + 2 * n + 6]);
      y3 = fmaf(bcs[t * 32 + 2 * n + 7], h[n + 3], y3);
    }
    const float y = (y0 + y1) + (y2 + y3);
    const float ya = (y + xc * Dd) * (g / (1.f + __expf(-g)));
    *yp = f2bf(ya);
    xcp += DI; gp += 2 * DI; yp += DI;
  }
}

extern "C" void kernel_launch(void* const* d_in, const int* in_sizes, int n_in,
                              void* d_out, int out_size, void* d_ws, size_t ws_size,
                              hipStream_t stream) {
  const float* x     = (const float*)d_in[0];
  const float* ln_w  = (const float*)d_in[1];
  const float* ln_b  = (const float*)d_in[2];
  const float* W_in  = (const float*)d_in[3];
  const float* b_in  = (const float*)d_in[4];
  const float* cw    = (const float*)d_in[5];
  const float* cb    = (const float*)d_in[6];
  const float* A_log = (const float*)d_in[7];
  const float* Dv    = (const float*)d_in[8];
  const float* W_x   = (const float*)d_in[9];
  const float* b_x   = (const float*)d_in[10];
  const float* W_out = (const float*)d_in[11];
  const float* b_out = (const float*)d_in[12];

  char* ws = (char*)d_ws;
  size_t off = 0;
  auto alloc = [&](size_t bytes) {
    void* p = ws + off;
    off += (bytes + 255) & ~(size_t)255;
    return p;
  };
  u16* WinT  = (u16*)alloc((size_t)(2 * DI) * DM * 2);
  u16* WoutT = (u16*)alloc((size_t)DM * DI * 2);
  u16* xn    = (u16*)alloc((size_t)TOKENS * DM * 2);  // 16 MB; reused as F after GEMM1
  u16* xg    = (u16*)alloc((size_t)TOKENS * (2 * DI) * 2);
  u16* xconv = (u16*)alloc((size_t)TOKENS * DI * 2);
  float* BC  = (float*)alloc((size_t)TOKENS * 32 * 4);
  u16* yact  = (u16*)alloc((size_t)TOKENS * DI * 2);
  float* F   = (float*)xn;  // 4*32*2048*16*4 = 16 MB, same size; xn dead after GEMM1
  (void)ws_size; (void)in_sizes; (void)n_in; (void)out_size;

  transpose_to_bf16<<<(DM / 64) * ((2 * DI) / 64), 256, 0, stream>>>(W_in, WinT, DM, 2 * DI);
  transpose_to_bf16<<<(DI / 64) * (DM / 64), 256, 0, stream>>>(W_out, WoutT, DI, DM);
  layernorm_bf16<<<TOKENS, 256, 0, stream>>>(x, ln_w, ln_b, xn);
  gemm_bt<0><<<(TOKENS / 128) * ((2 * DI) / 128), 256, 0, stream>>>(
      xn, WinT, b_in, nullptr, xg, TOKENS, 2 * DI, DM);
  conv_bc<<<TOKENS, 256, 0, stream>>>(xg, cw, cb, W_x, b_x, xconv, BC);
  scan_passA<<<4 * 8 * NCH, 256, 0, stream>>>(xconv, BC, A_log, F);
  scan_passB<<<512, 256, 0, stream>>>(A_log, F);
  scan_passC<<<4 * 8 * NCH, 256, 0, stream>>>(xconv, xg, BC, A_log, Dv, F, yact);
  gemm_bt<1><<<(TOKENS / 128) * (DM / 128), 256, 0, stream>>>(
      yact, WoutT, b_out, x, d_out, TOKENS, DM, DI);
}

// Round 4
// 428.831 us; speedup vs baseline: 4.2117x; 1.1266x over previous
//
#include <hip/hip_runtime.h>
#include <stdint.h>

typedef unsigned short u16;
typedef short bf16x8 __attribute__((ext_vector_type(8)));
typedef float f32x4 __attribute__((ext_vector_type(4)));

#define TOKENS 8192
#define SEQ 2048
#define DM 1024
#define DI 2048
#define NCH 32   // time chunks per sequence
#define CLEN 64  // SEQ / NCH

__device__ __forceinline__ float bf2f(u16 u) {
  union { uint32_t i; float f; } v; v.i = ((uint32_t)u) << 16; return v.f;
}
__device__ __forceinline__ u16 f2bf(float f) {
  union { float f; uint32_t i; } v; v.f = f;
  uint32_t r = v.i + 0x7FFFu + ((v.i >> 16) & 1u);
  return (u16)(r >> 16);
}

__device__ __forceinline__ void g2lds16(const void* g, void* l) {
  __builtin_amdgcn_global_load_lds(
      (const __attribute__((address_space(1))) uint32_t*)g,
      (__attribute__((address_space(3))) uint32_t*)l, 16, 0, 0);
}

// ---------------- transpose fp32 [R][C] -> bf16 [C][R] ----------------
__global__ __launch_bounds__(256)
void transpose_to_bf16(const float* __restrict__ src, u16* __restrict__ dst,
                       int R, int C) {
  __shared__ float tile[64][65];
  const int i = threadIdx.x;
  const int tilesC = C >> 6;
  const int br = blockIdx.x / tilesC, bc = blockIdx.x % tilesC;
  const int r0 = br << 6, c0 = bc << 6;
  const int cx = (i & 15) << 2, ry = i >> 4;
#pragma unroll
  for (int p = 0; p < 4; ++p) {
    int row = ry + p * 16;
    float4 v = *(const float4*)&src[(size_t)(r0 + row) * C + c0 + cx];
    tile[row][cx + 0] = v.x; tile[row][cx + 1] = v.y;
    tile[row][cx + 2] = v.z; tile[row][cx + 3] = v.w;
  }
  __syncthreads();
#pragma unroll
  for (int p = 0; p < 4; ++p) {
    int cr = ry + p * 16;  // output row = source col c0+cr
    ushort4 o;
    o.x = f2bf(tile[cx + 0][cr]); o.y = f2bf(tile[cx + 1][cr]);
    o.z = f2bf(tile[cx + 2][cr]); o.w = f2bf(tile[cx + 3][cr]);
    *(ushort4*)&dst[(size_t)(c0 + cr) * R + r0 + cx] = o;
  }
}

// ---------------- transpose W_x fp32 [2048][32] -> bf16 [32][2048] ----------------
__global__ __launch_bounds__(256)
void txpose_wx(const float* __restrict__ src, u16* __restrict__ dst) {
  const int gid = blockIdx.x * 256 + threadIdx.x;  // 65536
  const int k = gid >> 5, n = gid & 31;
  dst[(size_t)n * DI + k] = f2bf(src[gid]);
}

// ---------------- layernorm fp32 -> bf16 ----------------
__global__ __launch_bounds__(256)
void layernorm_bf16(const float* __restrict__ x, const float* __restrict__ lw,
                    const float* __restrict__ lb, u16* __restrict__ xn) {
  const int row = blockIdx.x, tid = threadIdx.x;
  const float4 v = *(const float4*)&x[(size_t)row * DM + tid * 4];
  float s = v.x + v.y + v.z + v.w;
  float q = v.x * v.x + v.y * v.y + v.z * v.z + v.w * v.w;
#pragma unroll
  for (int m = 1; m < 64; m <<= 1) { s += __shfl_xor(s, m); q += __shfl_xor(q, m); }
  __shared__ float red[8];
  const int w = tid >> 6, lane = tid & 63;
  if (lane == 0) { red[w] = s; red[4 + w] = q; }
  __syncthreads();
  s = red[0] + red[1] + red[2] + red[3];
  q = red[4] + red[5] + red[6] + red[7];
  const float mu = s * (1.f / DM);
  const float var = q * (1.f / DM) - mu * mu;
  const float rs = rsqrtf(var + 1e-5f);
  const float4 wv = *(const float4*)&lw[tid * 4];
  const float4 bv = *(const float4*)&lb[tid * 4];
  ushort4 o;
  o.x = f2bf((v.x - mu) * rs * wv.x + bv.x);
  o.y = f2bf((v.y - mu) * rs * wv.y + bv.y);
  o.z = f2bf((v.z - mu) * rs * wv.z + bv.z);
  o.w = f2bf((v.w - mu) * rs * wv.w + bv.w);
  *(ushort4*)&xn[(size_t)row * DM + tid * 4] = o;
}

// ---------------- bf16 MFMA GEMM: C = A[M][K] * Bt[N][K]^T + bias ----------------
template <int EPI>
__global__ __launch_bounds__(256)
void gemm_bt(const u16* __restrict__ A, const u16* __restrict__ Bt,
             const float* __restrict__ bias, const float* __restrict__ resid,
             void* __restrict__ out, int M, int N, int K) {
  __shared__ __align__(16) u16 As[128 * 64];
  __shared__ __align__(16) u16 Bs[128 * 64];
  const int tid = threadIdx.x, w = tid >> 6, lane = tid & 63;
  const int ntiles = N >> 7;
  const int tm = blockIdx.x / ntiles, tn = blockIdx.x % ntiles;
  const int m0 = tm << 7, n0 = tn << 7;
  f32x4 acc[4][4];
#pragma unroll
  for (int mi = 0; mi < 4; ++mi)
#pragma unroll
    for (int ni = 0; ni < 4; ++ni) acc[mi][ni] = (f32x4){0.f, 0.f, 0.f, 0.f};

  const int chunkbase = w * 64 + lane;
  const int wm = (w >> 1) * 64, wn = (w & 1) * 64;
  const int fr = lane & 15, fg = lane >> 4;

  for (int kt = 0; kt < K; kt += 64) {
#pragma unroll
    for (int i = 0; i < 4; ++i) {
      int ch = chunkbase + i * 256;
      int row = ch >> 3, c16 = ch & 7;
      g2lds16(A + (size_t)(m0 + row) * K + kt + c16 * 8,
              (u16*)As + (size_t)(w * 64 + i * 256) * 8);
      g2lds16(Bt + (size_t)(n0 + row) * K + kt + c16 * 8,
              (u16*)Bs + (size_t)(w * 64 + i * 256) * 8);
    }
    __syncthreads();
#pragma unroll
    for (int ks = 0; ks < 2; ++ks) {
      bf16x8 af[4], bfr[4];
#pragma unroll
      for (int mi = 0; mi < 4; ++mi)
        af[mi] = *(const bf16x8*)&As[(wm + mi * 16 + fr) * 64 + ks * 32 + fg * 8];
#pragma unroll
      for (int ni = 0; ni < 4; ++ni)
        bfr[ni] = *(const bf16x8*)&Bs[(wn + ni * 16 + fr) * 64 + ks * 32 + fg * 8];
#pragma unroll
      for (int mi = 0; mi < 4; ++mi)
#pragma unroll
        for (int ni = 0; ni < 4; ++ni)
          acc[mi][ni] = __builtin_amdgcn_mfma_f32_16x16x32_bf16(
              af[mi], bfr[ni], acc[mi][ni], 0, 0, 0);
    }
    __syncthreads();
  }
#pragma unroll
  for (int mi = 0; mi < 4; ++mi)
#pragma unroll
    for (int ni = 0; ni < 4; ++ni) {
      const int col = n0 + wn + ni * 16 + fr;
      const float bcol = bias[col];
#pragma unroll
      for (int j = 0; j < 4; ++j) {
        const int row = m0 + wm + mi * 16 + fg * 4 + j;
        float v = acc[mi][ni][j] + bcol;
        if (EPI == 1) {
          ((float*)out)[(size_t)row * N + col] = v + resid[(size_t)row * N + col];
        } else {
          ((u16*)out)[(size_t)row * N + col] = f2bf(v);
        }
      }
    }
}

// ---------------- causal conv1d + SiLU (elementwise) ----------------
// one block per token; 256 threads x 8 channels
__global__ __launch_bounds__(256)
void conv_silu(const u16* __restrict__ xg, const float* __restrict__ cw,
               const float* __restrict__ cb, u16* __restrict__ xconv) {
  const int t = blockIdx.x;
  const int s = t & (SEQ - 1);
  const int d = threadIdx.x * 8;
  float xv[4][8];
#pragma unroll
  for (int j = 0; j < 4; ++j) {
    const int ss = s - 3 + j;
    if (ss >= 0) {
      uint4 u = *(const uint4*)&xg[(size_t)(t - 3 + j) * (2 * DI) + d];
      const u16* pu = (const u16*)&u;
#pragma unroll
      for (int q = 0; q < 8; ++q) xv[j][q] = bf2f(pu[q]);
    } else {
#pragma unroll
      for (int q = 0; q < 8; ++q) xv[j][q] = 0.f;
    }
  }
  u16 outp[8];
#pragma unroll
  for (int q = 0; q < 8; ++q) {
    const float4 wq = *(const float4*)&cw[(d + q) * 4];
    float a = cb[d + q] + wq.x * xv[0][q] + wq.y * xv[1][q] + wq.z * xv[2][q] +
              wq.w * xv[3][q];
    outp[q] = f2bf(a / (1.f + __expf(-a)));
  }
  *(uint4*)&xconv[(size_t)t * DI + d] = *(const uint4*)outp;
}

// ---------------- BC projection: split-K MFMA GEMM ----------------
// BCp[ksplit][8192][32] partial = xconv[M][Kslice] @ wxT[32][Kslice]^T
__global__ __launch_bounds__(256)
void bc_gemm(const u16* __restrict__ xconv, const u16* __restrict__ wxT,
             float* __restrict__ BCp) {
  __shared__ __align__(16) u16 As[128 * 64];  // 16 KB
  __shared__ __align__(16) u16 Bs[32 * 64];   // 4 KB
  const int tid = threadIdx.x, w = tid >> 6, lane = tid & 63;
  const int mt = blockIdx.x & 63;        // 64 M-tiles of 128
  const int ks_id = blockIdx.x >> 6;     // 4 K-splits of 512
  const int m0 = mt << 7;
  const int k0 = ks_id << 9;
  const int fr = lane & 15, fg = lane >> 4;
  f32x4 acc[2][2];
#pragma unroll
  for (int mf = 0; mf < 2; ++mf)
#pragma unroll
    for (int nf = 0; nf < 2; ++nf) acc[mf][nf] = (f32x4){0.f, 0.f, 0.f, 0.f};

  for (int kt = k0; kt < k0 + 512; kt += 64) {
#pragma unroll
    for (int i = 0; i < 4; ++i) {
      int ch = w * 64 + lane + i * 256;
      int row = ch >> 3, c16 = ch & 7;
      g2lds16(xconv + (size_t)(m0 + row) * DI + kt + c16 * 8,
              (u16*)As + (size_t)(w * 64 + i * 256) * 8);
    }
    {
      int row = tid >> 3, c16 = tid & 7;
      g2lds16(wxT + (size_t)row * DI + kt + c16 * 8,
              (u16*)Bs + (size_t)(w * 64) * 8);
    }
    __syncthreads();
#pragma unroll
    for (int ks = 0; ks < 2; ++ks) {
      bf16x8 af[2], bfr[2];
#pragma unroll
      for (int mf = 0; mf < 2; ++mf)
        af[mf] = *(const bf16x8*)&As[(w * 32 + mf * 16 + fr) * 64 + ks * 32 + fg * 8];
#pragma unroll
      for (int nf = 0; nf < 2; ++nf)
        bfr[nf] = *(const bf16x8*)&Bs[(nf * 16 + fr) * 64 + ks * 32 + fg * 8];
#pragma unroll
      for (int mf = 0; mf < 2; ++mf)
#pragma unroll
        for (int nf = 0; nf < 2; ++nf)
          acc[mf][nf] = __builtin_amdgcn_mfma_f32_16x16x32_bf16(
              af[mf], bfr[nf], acc[mf][nf], 0, 0, 0);
    }
    __syncthreads();
  }
#pragma unroll
  for (int mf = 0; mf < 2; ++mf)
#pragma unroll
    for (int nf = 0; nf < 2; ++nf) {
      const int col = nf * 16 + fr;
#pragma unroll
      for (int j = 0; j < 4; ++j) {
        const int row = m0 + w * 32 + mf * 16 + fg * 4 + j;
        BCp[((size_t)ks_id * TOKENS + row) * 32 + col] = acc[mf][nf][j];
      }
    }
}

// ---------------- reduce split-K partials + bias + B/C interleave ----------------
__global__ __launch_bounds__(256)
void bc_reduce(const float* __restrict__ BCp, const float* __restrict__ bx,
               float* __restrict__ BC) {
  const int gid = blockIdx.x * 256 + threadIdx.x;  // 8192*32
  const int c = gid & 31;
  const size_t t = gid >> 5;
  float s = bx[c] + BCp[t * 32 + c] + BCp[((size_t)TOKENS + t) * 32 + c] +
            BCp[((size_t)2 * TOKENS + t) * 32 + c] +
            BCp[((size_t)3 * TOKENS + t) * 32 + c];
  const int dc = (c < 16) ? 2 * c : 2 * (c - 16) + 1;
  BC[t * 32 + dc] = s;
}

// ---------------- chunked selective scan ----------------
// Pass A: per (b, chunk, d) local recurrence with h0=0; store chunk-final state.
__global__ __launch_bounds__(256)
void scan_passA(const u16* __restrict__ xconv, const float* __restrict__ BC,
                const float* __restrict__ A_log, float* __restrict__ F) {
  __shared__ float bcs[CLEN * 32];
  const int blk = blockIdx.x;  // [b:2][dg:3][j:5]
  const int j = blk & (NCH - 1);
  const int dg = (blk >> 5) & 7;
  const int b = blk >> 8;
  const int tid = threadIdx.x;
  const int d = dg * 256 + tid;
  const int t0 = j * CLEN;
  {
    const float4* s4 = (const float4*)(BC + (size_t)(b * SEQ + t0) * 32);
    float4* d4 = (float4*)bcs;
#pragma unroll
    for (int i = 0; i < 2; ++i) d4[tid + i * 256] = s4[tid + i * 256];
  }
  float dA[16], h[16];
#pragma unroll
  for (int n = 0; n < 16; ++n) {
    dA[n] = __expf(-__expf(A_log[d * 16 + n]));
    h[n] = 0.f;
  }
  __syncthreads();
  const u16* xcp = xconv + (size_t)(b * SEQ + t0) * DI + d;
  for (int t = 0; t < CLEN; ++t) {
    const float xc = bf2f(*xcp);
    xcp += DI;
#pragma unroll
    for (int n = 0; n < 16; ++n)
      h[n] = fmaf(dA[n], h[n], xc * bcs[t * 32 + 2 * n]);
  }
  float* fp = F + ((size_t)((b * NCH + j) * DI) + d) * 16;
#pragma unroll
  for (int n = 0; n < 16; n += 4) {
    float4 v = {h[n], h[n + 1], h[n + 2], h[n + 3]};
    *(float4*)&fp[n] = v;
  }
}

// Pass B: per (b,d,n): sequential scan over the 32 chunk finals -> carry-in states (in place).
__global__ __launch_bounds__(256)
void scan_passB(const float* __restrict__ A_log, float* __restrict__ F) {
  const int gid = blockIdx.x * 256 + threadIdx.x;  // (b, d, n)
  const int n = gid & 15;
  const int d = (gid >> 4) & (DI - 1);
  const int b = gid >> 15;
  const float dAL = __expf(-(float)CLEN * __expf(A_log[d * 16 + n]));
  float carry = 0.f;
  const size_t base = ((size_t)(b * NCH) * DI + d) * 16 + n;
  const size_t stride = (size_t)DI * 16;
  for (int j = 0; j < NCH; ++j) {
    const size_t idx = base + (size_t)j * stride;
    const float f = F[idx];
    F[idx] = carry;
    carry = fmaf(dAL, carry, f);
  }
}

// Pass C: re-run recurrence seeded with carry-in; fuse C-dot, +x*D, *silu(gate), bf16 store.
__global__ __launch_bounds__(256)
void scan_passC(const u16* __restrict__ xconv, const u16* __restrict__ xg,
                const float* __restrict__ BC, const float* __restrict__ A_log,
                const float* __restrict__ Dv, const float* __restrict__ F,
                u16* __restrict__ yact) {
  __shared__ float bcs[CLEN * 32];
  const int blk = blockIdx.x;
  const int j = blk & (NCH - 1);
  const int dg = (blk >> 5) & 7;
  const int b = blk >> 8;
  const int tid = threadIdx.x;
  const int d = dg * 256 + tid;
  const int t0 = j * CLEN;
  {
    const float4* s4 = (const float4*)(BC + (size_t)(b * SEQ + t0) * 32);
    float4* d4 = (float4*)bcs;
#pragma unroll
    for (int i = 0; i < 2; ++i) d4[tid + i * 256] = s4[tid + i * 256];
  }
  float dA[16], h[16];
  const float* fp = F + ((size_t)((b * NCH + j) * DI) + d) * 16;
#pragma unroll
  for (int n = 0; n < 16; n += 4) {
    float4 v = *(const float4*)&fp[n];
    h[n] = v.x; h[n + 1] = v.y; h[n + 2] = v.z; h[n + 3] = v.w;
  }
#pragma unroll
  for (int n = 0; n < 16; ++n) dA[n] = __expf(-__expf(A_log[d * 16 + n]));
  const float Dd = Dv[d];
  __syncthreads();
  const u16* xcp = xconv + (size_t)(b * SEQ + t0) * DI + d;
  const u16* gp = xg + (size_t)(b * SEQ + t0) * (2 * DI) + DI + d;
  u16* yp = yact + (size_t)(b * SEQ + t0) * DI + d;
  for (int t = 0; t < CLEN; ++t) {
    const float xc = bf2f(*xcp);
    const float g = bf2f(*gp);
    float y0 = 0.f, y1 = 0.f, y2 = 0.f, y3 = 0.f;
#pragma unroll
    for (int n = 0; n < 16; n += 4) {
      h[n]     = fmaf(dA[n],     h[n],     xc * bcs[t * 32 + 2 * n]);
      y0 = fmaf(bcs[t * 32 + 2 * n + 1], h[n], y0);
      h[n + 1] = fmaf(dA[n + 1], h[n + 1], xc * bcs[t * 32 + 2 * n + 2]);
      y1 = fmaf(bcs[t * 32 + 2 * n + 3], h[n + 1], y1);
      h[n + 2] = fmaf(dA[n + 2], h[n + 2], xc * bcs[t * 32 + 2 * n + 4]);
      y2 = fmaf(bcs[t * 32 + 2 * n + 5], h[n + 2], y2);
      h[n + 3] = fmaf(dA[n + 3], h[n + 3], xc * bcs[t * 32 + 2 * n + 6]);
      y3 = fmaf(bcs[t * 32 + 2 * n + 7], h[n + 3], y3);
    }
    const float y = (y0 + y1) + (y2 + y3);
    const float ya = (y + xc * Dd) * (g / (1.f + __expf(-g)));
    *yp = f2bf(ya);
    xcp += DI; gp += 2 * DI; yp += DI;
  }
}

extern "C" void kernel_launch(void* const* d_in, const int* in_sizes, int n_in,
                              void* d_out, int out_size, void* d_ws, size_t ws_size,
                              hipStream_t stream) {
  const float* x     = (const float*)d_in[0];
  const float* ln_w  = (const float*)d_in[1];
  const float* ln_b  = (const float*)d_in[2];
  const float* W_in  = (const float*)d_in[3];
  const float* b_in  = (const float*)d_in[4];
  const float* cw    = (const float*)d_in[5];
  const float* cb    = (const float*)d_in[6];
  const float* A_log = (const float*)d_in[7];
  const float* Dv    = (const float*)d_in[8];
  const float* W_x   = (const float*)d_in[9];
  const float* b_x   = (const float*)d_in[10];
  const float* W_out = (const float*)d_in[11];
  const float* b_out = (const float*)d_in[12];

  char* ws = (char*)d_ws;
  size_t off = 0;
  auto alloc = [&](size_t bytes) {
    void* p = ws + off;
    off += (bytes + 255) & ~(size_t)255;
    return p;
  };
  u16* WinT  = (u16*)alloc((size_t)(2 * DI) * DM * 2);
  u16* WoutT = (u16*)alloc((size_t)DM * DI * 2);
  u16* xn    = (u16*)alloc((size_t)TOKENS * DM * 2);  // 16 MB; reused as F after GEMM1
  u16* xg    = (u16*)alloc((size_t)TOKENS * (2 * DI) * 2);
  u16* xconv = (u16*)alloc((size_t)TOKENS * DI * 2);
  float* BC  = (float*)alloc((size_t)TOKENS * 32 * 4);
  u16* yact  = (u16*)alloc((size_t)TOKENS * DI * 2);
  u16* WxT   = (u16*)alloc((size_t)32 * DI * 2);       // 128 KB
  float* BCp = (float*)alloc((size_t)4 * TOKENS * 32 * 4);  // 4 MB
  float* F   = (float*)xn;  // 4*32*2048*16*4 = 16 MB, same size; xn dead after GEMM1
  (void)ws_size; (void)in_sizes; (void)n_in; (void)out_size;

  transpose_to_bf16<<<(DM / 64) * ((2 * DI) / 64), 256, 0, stream>>>(W_in, WinT, DM, 2 * DI);
  transpose_to_bf16<<<(DI / 64) * (DM / 64), 256, 0, stream>>>(W_out, WoutT, DI, DM);
  txpose_wx<<<(DI * 32) / 256, 256, 0, stream>>>(W_x, WxT);
  layernorm_bf16<<<TOKENS, 256, 0, stream>>>(x, ln_w, ln_b, xn);
  gemm_bt<0><<<(TOKENS / 128) * ((2 * DI) / 128), 256, 0, stream>>>(
      xn, WinT, b_in, nullptr, xg, TOKENS, 2 * DI, DM);
  conv_silu<<<TOKENS, 256, 0, stream>>>(xg, cw, cb, xconv);
  bc_gemm<<<256, 256, 0, stream>>>(xconv, WxT, BCp);
  bc_reduce<<<(TOKENS * 32) / 256, 256, 0, stream>>>(BCp, b_x, BC);
  scan_passA<<<4 * 8 * NCH, 256, 0, stream>>>(xconv, BC, A_log, F);
  scan_passB<<<512, 256, 0, stream>>>(A_log, F);
  scan_passC<<<4 * 8 * NCH, 256, 0, stream>>>(xconv, xg, BC, A_log, Dv, F, yact);
  gemm_bt<1><<<(TOKENS / 128) * (DM / 128), 256, 0, stream>>>(
      yact, WoutT, b_out, x, d_out, TOKENS, DM, DI);
}

// Round 5
// 413.253 us; speedup vs baseline: 4.3705x; 1.0377x over previous
//
#include <hip/hip_runtime.h>
#include <stdint.h>

typedef unsigned short u16;
typedef short bf16x8 __attribute__((ext_vector_type(8)));
typedef float f32x4 __attribute__((ext_vector_type(4)));

#define TOKENS 8192
#define SEQ 2048
#define DM 1024
#define DI 2048
#define NCH 32   // time chunks per sequence
#define CLEN 64  // SEQ / NCH

__device__ __forceinline__ float bf2f(u16 u) {
  union { uint32_t i; float f; } v; v.i = ((uint32_t)u) << 16; return v.f;
}
__device__ __forceinline__ u16 f2bf(float f) {
  union { float f; uint32_t i; } v; v.f = f;
  uint32_t r = v.i + 0x7FFFu + ((v.i >> 16) & 1u);
  return (u16)(r >> 16);
}

__device__ __forceinline__ void g2lds16(const void* g, void* l) {
  __builtin_amdgcn_global_load_lds(
      (const __attribute__((address_space(1))) uint32_t*)g,
      (__attribute__((address_space(3))) uint32_t*)l, 16, 0, 0);
}

// ---------------- transpose fp32 [R][C] -> bf16 [C][R] ----------------
__global__ __launch_bounds__(256)
void transpose_to_bf16(const float* __restrict__ src, u16* __restrict__ dst,
                       int R, int C) {
  __shared__ float tile[64][65];
  const int i = threadIdx.x;
  const int tilesC = C >> 6;
  const int br = blockIdx.x / tilesC, bc = blockIdx.x % tilesC;
  const int r0 = br << 6, c0 = bc << 6;
  const int cx = (i & 15) << 2, ry = i >> 4;
#pragma unroll
  for (int p = 0; p < 4; ++p) {
    int row = ry + p * 16;
    float4 v = *(const float4*)&src[(size_t)(r0 + row) * C + c0 + cx];
    tile[row][cx + 0] = v.x; tile[row][cx + 1] = v.y;
    tile[row][cx + 2] = v.z; tile[row][cx + 3] = v.w;
  }
  __syncthreads();
#pragma unroll
  for (int p = 0; p < 4; ++p) {
    int cr = ry + p * 16;  // output row = source col c0+cr
    ushort4 o;
    o.x = f2bf(tile[cx + 0][cr]); o.y = f2bf(tile[cx + 1][cr]);
    o.z = f2bf(tile[cx + 2][cr]); o.w = f2bf(tile[cx + 3][cr]);
    *(ushort4*)&dst[(size_t)(c0 + cr) * R + r0 + cx] = o;
  }
}

// ---------------- transpose W_x fp32 [2048][32] -> bf16 [32][2048] ----------------
__global__ __launch_bounds__(256)
void txpose_wx(const float* __restrict__ src, u16* __restrict__ dst) {
  const int gid = blockIdx.x * 256 + threadIdx.x;  // 65536
  const int k = gid >> 5, n = gid & 31;
  dst[(size_t)n * DI + k] = f2bf(src[gid]);
}

// ---------------- layernorm fp32 -> bf16 ----------------
__global__ __launch_bounds__(256)
void layernorm_bf16(const float* __restrict__ x, const float* __restrict__ lw,
                    const float* __restrict__ lb, u16* __restrict__ xn) {
  const int row = blockIdx.x, tid = threadIdx.x;
  const float4 v = *(const float4*)&x[(size_t)row * DM + tid * 4];
  float s = v.x + v.y + v.z + v.w;
  float q = v.x * v.x + v.y * v.y + v.z * v.z + v.w * v.w;
#pragma unroll
  for (int m = 1; m < 64; m <<= 1) { s += __shfl_xor(s, m); q += __shfl_xor(q, m); }
  __shared__ float red[8];
  const int w = tid >> 6, lane = tid & 63;
  if (lane == 0) { red[w] = s; red[4 + w] = q; }
  __syncthreads();
  s = red[0] + red[1] + red[2] + red[3];
  q = red[4] + red[5] + red[6] + red[7];
  const float mu = s * (1.f / DM);
  const float var = q * (1.f / DM) - mu * mu;
  const float rs = rsqrtf(var + 1e-5f);
  const float4 wv = *(const float4*)&lw[tid * 4];
  const float4 bv = *(const float4*)&lb[tid * 4];
  ushort4 o;
  o.x = f2bf((v.x - mu) * rs * wv.x + bv.x);
  o.y = f2bf((v.y - mu) * rs * wv.y + bv.y);
  o.z = f2bf((v.z - mu) * rs * wv.z + bv.z);
  o.w = f2bf((v.w - mu) * rs * wv.w + bv.w);
  *(ushort4*)&xn[(size_t)row * DM + tid * 4] = o;
}

// ---------------- pipelined bf16 MFMA GEMM: C = A[M][K] * Bt[N][K]^T + bias --------
// BM=128, BN=256, BK=64; 8 waves (2Mx4N); 3-buffer LDS pipeline, counted vmcnt;
// XOR chunk swizzle (rule #21: linear LDS dest + inverse-swizzled global source
// + swizzled read). EPI 0: out bf16.  EPI 1: out fp32 = acc + bias + resid.
#define TILE_U16 ((128 + 256) * 64)
template <int EPI>
__global__ __launch_bounds__(512, 1)
void gemm3(const u16* __restrict__ A, const u16* __restrict__ Bt,
           const float* __restrict__ bias, const float* __restrict__ resid,
           void* __restrict__ out, int M, int N, int K) {
  __shared__ __align__(16) u16 lds[3 * TILE_U16];
  const int tid = threadIdx.x, wid = tid >> 6, lane = tid & 63;
  const int ntiles = N >> 8;
  int bid = blockIdx.x;
  {  // XCD-aware swizzle (grid % 8 == 0 for our shapes)
    const int cpx = gridDim.x >> 3;
    bid = (bid & 7) * cpx + (bid >> 3);
  }
  const int tm = bid / ntiles, tn = bid % ntiles;
  const int m0 = tm << 7, n0 = tn << 8;
  const int wm = (wid >> 2) * 64, wn = (wid & 3) * 64;
  const int fr = lane & 15, fg = lane >> 4;
  const int c0 = (fg ^ (fr & 7)) << 4;  // swizzled byte offset of ks0 chunk
  const int NK = K >> 6;

  f32x4 acc[4][4];
#pragma unroll
  for (int mi = 0; mi < 4; ++mi)
#pragma unroll
    for (int ni = 0; ni < 4; ++ni) acc[mi][ni] = (f32x4){0.f, 0.f, 0.f, 0.f};

  auto stage = [&](int T) {
    const int kt = T << 6;
    u16* buf = lds + (T % 3) * TILE_U16;
    // A half: 128 rows x 64 k = 1024 chunks of 16B; 2 loads/thread
#pragma unroll
    for (int i = 0; i < 2; ++i) {
      const int s = i * 512 + tid;
      const int row = s >> 3, l = (s & 7) ^ (row & 7);
      g2lds16(A + (size_t)(m0 + row) * K + kt + l * 8, buf + s * 8);
    }
    u16* bufB = buf + 128 * 64;
#pragma unroll
    for (int i = 0; i < 4; ++i) {
      const int s = i * 512 + tid;
      const int row = s >> 3, l = (s & 7) ^ (row & 7);
      g2lds16(Bt + (size_t)(n0 + row) * K + kt + l * 8, bufB + s * 8);
    }
  };

  stage(0); stage(1); stage(2);                 // 18 loads in flight
  asm volatile("s_waitcnt vmcnt(12)" ::: "memory");  // tile 0 landed
  __builtin_amdgcn_s_barrier();
  asm volatile("" ::: "memory");

  for (int T = 0; T < NK; ++T) {
    const char* bufA = (const char*)(lds + (T % 3) * TILE_U16);
    const char* bufB = bufA + 128 * 64 * 2;
    bf16x8 af[2][4], bf_[2][4];
#pragma unroll
    for (int ks = 0; ks < 2; ++ks) {
      const int cb = c0 ^ (ks << 6);
#pragma unroll
      for (int mi = 0; mi < 4; ++mi)
        af[ks][mi] = *(const bf16x8*)(bufA + (wm + mi * 16 + fr) * 128 + cb);
#pragma unroll
      for (int ni = 0; ni < 4; ++ni)
        bf_[ks][ni] = *(const bf16x8*)(bufB + (wn + ni * 16 + fr) * 128 + cb);
    }
    __builtin_amdgcn_s_setprio(1);
#pragma unroll
    for (int ks = 0; ks < 2; ++ks)
#pragma unroll
      for (int mi = 0; mi < 4; ++mi)
#pragma unroll
        for (int ni = 0; ni < 4; ++ni)
          acc[mi][ni] = __builtin_amdgcn_mfma_f32_16x16x32_bf16(
              af[ks][mi], bf_[ks][ni], acc[mi][ni], 0, 0, 0);
    __builtin_amdgcn_s_setprio(0);
    // all frags consumed by MFMA (lgkm waits inserted before use) -> buffer free
    __builtin_amdgcn_s_barrier();
    asm volatile("" ::: "memory");
    if (T + 3 < NK) {
      stage(T + 3);
      asm volatile("s_waitcnt vmcnt(12)" ::: "memory");  // tile T+1 complete
    } else if (T + 2 < NK) {
      asm volatile("s_waitcnt vmcnt(6)" ::: "memory");   // tail: T+1 complete
    } else if (T + 1 < NK) {
      asm volatile("s_waitcnt vmcnt(0)" ::: "memory");   // tail: last tile
    }
    __builtin_amdgcn_s_barrier();
    asm volatile("" ::: "memory");
  }

#pragma unroll
  for (int mi = 0; mi < 4; ++mi)
#pragma unroll
    for (int ni = 0; ni < 4; ++ni) {
      const int col = n0 + wn + ni * 16 + fr;
      const float bcol = bias[col];
#pragma unroll
      for (int j = 0; j < 4; ++j) {
        const int row = m0 + wm + mi * 16 + fg * 4 + j;
        float v = acc[mi][ni][j] + bcol;
        if (EPI == 1) {
          ((float*)out)[(size_t)row * N + col] = v + resid[(size_t)row * N + col];
        } else {
          ((u16*)out)[(size_t)row * N + col] = f2bf(v);
        }
      }
    }
}

// ---------------- causal conv1d + SiLU (elementwise) ----------------
__global__ __launch_bounds__(256)
void conv_silu(const u16* __restrict__ xg, const float* __restrict__ cw,
               const float* __restrict__ cb, u16* __restrict__ xconv) {
  const int t = blockIdx.x;
  const int s = t & (SEQ - 1);
  const int d = threadIdx.x * 8;
  float xv[4][8];
#pragma unroll
  for (int j = 0; j < 4; ++j) {
    const int ss = s - 3 + j;
    if (ss >= 0) {
      uint4 u = *(const uint4*)&xg[(size_t)(t - 3 + j) * (2 * DI) + d];
      const u16* pu = (const u16*)&u;
#pragma unroll
      for (int q = 0; q < 8; ++q) xv[j][q] = bf2f(pu[q]);
    } else {
#pragma unroll
      for (int q = 0; q < 8; ++q) xv[j][q] = 0.f;
    }
  }
  u16 outp[8];
#pragma unroll
  for (int q = 0; q < 8; ++q) {
    const float4 wq = *(const float4*)&cw[(d + q) * 4];
    float a = cb[d + q] + wq.x * xv[0][q] + wq.y * xv[1][q] + wq.z * xv[2][q] +
              wq.w * xv[3][q];
    outp[q] = f2bf(a / (1.f + __expf(-a)));
  }
  *(uint4*)&xconv[(size_t)t * DI + d] = *(const uint4*)outp;
}

// ---------------- BC projection: split-K MFMA GEMM ----------------
__global__ __launch_bounds__(256)
void bc_gemm(const u16* __restrict__ xconv, const u16* __restrict__ wxT,
             float* __restrict__ BCp) {
  __shared__ __align__(16) u16 As[128 * 64];
  __shared__ __align__(16) u16 Bs[32 * 64];
  const int tid = threadIdx.x, w = tid >> 6, lane = tid & 63;
  const int mt = blockIdx.x & 63;
  const int ks_id = blockIdx.x >> 6;
  const int m0 = mt << 7;
  const int k0 = ks_id << 9;
  const int fr = lane & 15, fg = lane >> 4;
  f32x4 acc[2][2];
#pragma unroll
  for (int mf = 0; mf < 2; ++mf)
#pragma unroll
    for (int nf = 0; nf < 2; ++nf) acc[mf][nf] = (f32x4){0.f, 0.f, 0.f, 0.f};

  for (int kt = k0; kt < k0 + 512; kt += 64) {
#pragma unroll
    for (int i = 0; i < 4; ++i) {
      int ch = w * 64 + lane + i * 256;
      int row = ch >> 3, c16 = ch & 7;
      g2lds16(xconv + (size_t)(m0 + row) * DI + kt + c16 * 8,
              (u16*)As + (size_t)(w * 64 + i * 256) * 8);
    }
    {
      int row = tid >> 3, c16 = tid & 7;
      g2lds16(wxT + (size_t)row * DI + kt + c16 * 8,
              (u16*)Bs + (size_t)(w * 64) * 8);
    }
    __syncthreads();
#pragma unroll
    for (int ks = 0; ks < 2; ++ks) {
      bf16x8 af[2], bfr[2];
#pragma unroll
      for (int mf = 0; mf < 2; ++mf)
        af[mf] = *(const bf16x8*)&As[(w * 32 + mf * 16 + fr) * 64 + ks * 32 + fg * 8];
#pragma unroll
      for (int nf = 0; nf < 2; ++nf)
        bfr[nf] = *(const bf16x8*)&Bs[(nf * 16 + fr) * 64 + ks * 32 + fg * 8];
#pragma unroll
      for (int mf = 0; mf < 2; ++mf)
#pragma unroll
        for (int nf = 0; nf < 2; ++nf)
          acc[mf][nf] = __builtin_amdgcn_mfma_f32_16x16x32_bf16(
              af[mf], bfr[nf], acc[mf][nf], 0, 0, 0);
    }
    __syncthreads();
  }
#pragma unroll
  for (int mf = 0; mf < 2; ++mf)
#pragma unroll
    for (int nf = 0; nf < 2; ++nf) {
      const int col = nf * 16 + fr;
#pragma unroll
      for (int j = 0; j < 4; ++j) {
        const int row = m0 + w * 32 + mf * 16 + fg * 4 + j;
        BCp[((size_t)ks_id * TOKENS + row) * 32 + col] = acc[mf][nf][j];
      }
    }
}

// ---------------- reduce split-K partials + bias + B/C interleave ----------------
__global__ __launch_bounds__(256)
void bc_reduce(const float* __restrict__ BCp, const float* __restrict__ bx,
               float* __restrict__ BC) {
  const int gid = blockIdx.x * 256 + threadIdx.x;
  const int c = gid & 31;
  const size_t t = gid >> 5;
  float s = bx[c] + BCp[t * 32 + c] + BCp[((size_t)TOKENS + t) * 32 + c] +
            BCp[((size_t)2 * TOKENS + t) * 32 + c] +
            BCp[((size_t)3 * TOKENS + t) * 32 + c];
  const int dc = (c < 16) ? 2 * c : 2 * (c - 16) + 1;
  BC[t * 32 + dc] = s;
}

// ---------------- chunked selective scan ----------------
__global__ __launch_bounds__(256)
void scan_passA(const u16* __restrict__ xconv, const float* __restrict__ BC,
                const float* __restrict__ A_log, float* __restrict__ F) {
  __shared__ float bcs[CLEN * 32];
  const int blk = blockIdx.x;
  const int j = blk & (NCH - 1);
  const int dg = (blk >> 5) & 7;
  const int b = blk >> 8;
  const int tid = threadIdx.x;
  const int d = dg * 256 + tid;
  const int t0 = j * CLEN;
  {
    const float4* s4 = (const float4*)(BC + (size_t)(b * SEQ + t0) * 32);
    float4* d4 = (float4*)bcs;
#pragma unroll
    for (int i = 0; i < 2; ++i) d4[tid + i * 256] = s4[tid + i * 256];
  }
  float dA[16], h[16];
#pragma unroll
  for (int n = 0; n < 16; ++n) {
    dA[n] = __expf(-__expf(A_log[d * 16 + n]));
    h[n] = 0.f;
  }
  __syncthreads();
  const u16* xcp = xconv + (size_t)(b * SEQ + t0) * DI + d;
  for (int t = 0; t < CLEN; ++t) {
    const float xc = bf2f(*xcp);
    xcp += DI;
#pragma unroll
    for (int n = 0; n < 16; ++n)
      h[n] = fmaf(dA[n], h[n], xc * bcs[t * 32 + 2 * n]);
  }
  float* fp = F + ((size_t)((b * NCH + j) * DI) + d) * 16;
#pragma unroll
  for (int n = 0; n < 16; n += 4) {
    float4 v = {h[n], h[n + 1], h[n + 2], h[n + 3]};
    *(float4*)&fp[n] = v;
  }
}

__global__ __launch_bounds__(256)
void scan_passB(const float* __restrict__ A_log, float* __restrict__ F) {
  const int gid = blockIdx.x * 256 + threadIdx.x;
  const int n = gid & 15;
  const int d = (gid >> 4) & (DI - 1);
  const int b = gid >> 15;
  const float dAL = __expf(-(float)CLEN * __expf(A_log[d * 16 + n]));
  float carry = 0.f;
  const size_t base = ((size_t)(b * NCH) * DI + d) * 16 + n;
  const size_t stride = (size_t)DI * 16;
  for (int j = 0; j < NCH; ++j) {
    const size_t idx = base + (size_t)j * stride;
    const float f = F[idx];
    F[idx] = carry;
    carry = fmaf(dAL, carry, f);
  }
}

__global__ __launch_bounds__(256)
void scan_passC(const u16* __restrict__ xconv, const u16* __restrict__ xg,
                const float* __restrict__ BC, const float* __restrict__ A_log,
                const float* __restrict__ Dv, const float* __restrict__ F,
                u16* __restrict__ yact) {
  __shared__ float bcs[CLEN * 32];
  const int blk = blockIdx.x;
  const int j = blk & (NCH - 1);
  const int dg = (blk >> 5) & 7;
  const int b = blk >> 8;
  const int tid = threadIdx.x;
  const int d = dg * 256 + tid;
  const int t0 = j * CLEN;
  {
    const float4* s4 = (const float4*)(BC + (size_t)(b * SEQ + t0) * 32);
    float4* d4 = (float4*)bcs;
#pragma unroll
    for (int i = 0; i < 2; ++i) d4[tid + i * 256] = s4[tid + i * 256];
  }
  float dA[16], h[16];
  const float* fp = F + ((size_t)((b * NCH + j) * DI) + d) * 16;
#pragma unroll
  for (int n = 0; n < 16; n += 4) {
    float4 v = *(const float4*)&fp[n];
    h[n] = v.x; h[n + 1] = v.y; h[n + 2] = v.z; h[n + 3] = v.w;
  }
#pragma unroll
  for (int n = 0; n < 16; ++n) dA[n] = __expf(-__expf(A_log[d * 16 + n]));
  const float Dd = Dv[d];
  __syncthreads();
  const u16* xcp = xconv + (size_t)(b * SEQ + t0) * DI + d;
  const u16* gp = xg + (size_t)(b * SEQ + t0) * (2 * DI) + DI + d;
  u16* yp = yact + (size_t)(b * SEQ + t0) * DI + d;
  for (int t = 0; t < CLEN; ++t) {
    const float xc = bf2f(*xcp);
    const float g = bf2f(*gp);
    float y0 = 0.f, y1 = 0.f, y2 = 0.f, y3 = 0.f;
#pragma unroll
    for (int n = 0; n < 16; n += 4) {
      h[n]     = fmaf(dA[n],     h[n],     xc * bcs[t * 32 + 2 * n]);
      y0 = fmaf(bcs[t * 32 + 2 * n + 1], h[n], y0);
      h[n + 1] = fmaf(dA[n + 1], h[n + 1], xc * bcs[t * 32 + 2 * n + 2]);
      y1 = fmaf(bcs[t * 32 + 2 * n + 3], h[n + 1], y1);
      h[n + 2] = fmaf(dA[n + 2], h[n + 2], xc * bcs[t * 32 + 2 * n + 4]);
      y2 = fmaf(bcs[t * 32 + 2 * n + 5], h[n + 2], y2);
      h[n + 3] = fmaf(dA[n + 3], h[n + 3], xc * bcs[t * 32 + 2 * n + 6]);
      y3 = fmaf(bcs[t * 32 + 2 * n + 7], h[n + 3], y3);
    }
    const float y = (y0 + y1) + (y2 + y3);
    const float ya = (y + xc * Dd) * (g / (1.f + __expf(-g)));
    *yp = f2bf(ya);
    xcp += DI; gp += 2 * DI; yp += DI;
  }
}

extern "C" void kernel_launch(void* const* d_in, const int* in_sizes, int n_in,
                              void* d_out, int out_size, void* d_ws, size_t ws_size,
                              hipStream_t stream) {
  const float* x     = (const float*)d_in[0];
  const float* ln_w  = (const float*)d_in[1];
  const float* ln_b  = (const float*)d_in[2];
  const float* W_in  = (const float*)d_in[3];
  const float* b_in  = (const float*)d_in[4];
  const float* cw    = (const float*)d_in[5];
  const float* cb    = (const float*)d_in[6];
  const float* A_log = (const float*)d_in[7];
  const float* Dv    = (const float*)d_in[8];
  const float* W_x   = (const float*)d_in[9];
  const float* b_x   = (const float*)d_in[10];
  const float* W_out = (const float*)d_in[11];
  const float* b_out = (const float*)d_in[12];

  char* ws = (char*)d_ws;
  size_t off = 0;
  auto alloc = [&](size_t bytes) {
    void* p = ws + off;
    off += (bytes + 255) & ~(size_t)255;
    return p;
  };
  u16* WinT  = (u16*)alloc((size_t)(2 * DI) * DM * 2);
  u16* WoutT = (u16*)alloc((size_t)DM * DI * 2);
  u16* xn    = (u16*)alloc((size_t)TOKENS * DM * 2);  // reused as F after GEMM1
  u16* xg    = (u16*)alloc((size_t)TOKENS * (2 * DI) * 2);
  u16* xconv = (u16*)alloc((size_t)TOKENS * DI * 2);
  float* BC  = (float*)alloc((size_t)TOKENS * 32 * 4);
  u16* yact  = (u16*)alloc((size_t)TOKENS * DI * 2);
  u16* WxT   = (u16*)alloc((size_t)32 * DI * 2);
  float* BCp = (float*)alloc((size_t)4 * TOKENS * 32 * 4);
  float* F   = (float*)xn;
  (void)ws_size; (void)in_sizes; (void)n_in; (void)out_size;

  transpose_to_bf16<<<(DM / 64) * ((2 * DI) / 64), 256, 0, stream>>>(W_in, WinT, DM, 2 * DI);
  transpose_to_bf16<<<(DI / 64) * (DM / 64), 256, 0, stream>>>(W_out, WoutT, DI, DM);
  txpose_wx<<<(DI * 32) / 256, 256, 0, stream>>>(W_x, WxT);
  layernorm_bf16<<<TOKENS, 256, 0, stream>>>(x, ln_w, ln_b, xn);
  gemm3<0><<<(TOKENS / 128) * ((2 * DI) / 256), 512, 0, stream>>>(
      xn, WinT, b_in, nullptr, xg, TOKENS, 2 * DI, DM);
  conv_silu<<<TOKENS, 256, 0, stream>>>(xg, cw, cb, xconv);
  bc_gemm<<<256, 256, 0, stream>>>(xconv, WxT, BCp);
  bc_reduce<<<(TOKENS * 32) / 256, 256, 0, stream>>>(BCp, b_x, BC);
  scan_passA<<<4 * 8 * NCH, 256, 0, stream>>>(xconv, BC, A_log, F);
  scan_passB<<<512, 256, 0, stream>>>(A_log, F);
  scan_passC<<<4 * 8 * NCH, 256, 0, stream>>>(xconv, xg, BC, A_log, Dv, F, yact);
  gemm3<1><<<(TOKENS / 128) * (DM / 256), 512, 0, stream>>>(
      yact, WoutT, b_out, x, d_out, TOKENS, DM, DI);
}

// Round 6
// 394.210 us; speedup vs baseline: 4.5816x; 1.0483x over previous
//
#include <hip/hip_runtime.h>
#include <stdint.h>

typedef unsigned short u16;
typedef short bf16x8 __attribute__((ext_vector_type(8)));
typedef float f32x4 __attribute__((ext_vector_type(4)));

#define TOKENS 8192
#define SEQ 2048
#define DM 1024
#define DI 2048
#define NCH 32   // time chunks per sequence
#define CLEN 64  // SEQ / NCH

__device__ __forceinline__ float bf2f(u16 u) {
  union { uint32_t i; float f; } v; v.i = ((uint32_t)u) << 16; return v.f;
}
__device__ __forceinline__ u16 f2bf(float f) {
  union { float f; uint32_t i; } v; v.f = f;
  uint32_t r = v.i + 0x7FFFu + ((v.i >> 16) & 1u);
  return (u16)(r >> 16);
}

__device__ __forceinline__ void g2lds16(const void* g, void* l) {
  __builtin_amdgcn_global_load_lds(
      (const __attribute__((address_space(1))) uint32_t*)g,
      (__attribute__((address_space(3))) uint32_t*)l, 16, 0, 0);
}

// ---------------- transpose fp32 [R][C] -> bf16 [C][R] ----------------
__global__ __launch_bounds__(256)
void transpose_to_bf16(const float* __restrict__ src, u16* __restrict__ dst,
                       int R, int C) {
  __shared__ float tile[64][65];
  const int i = threadIdx.x;
  const int tilesC = C >> 6;
  const int br = blockIdx.x / tilesC, bc = blockIdx.x % tilesC;
  const int r0 = br << 6, c0 = bc << 6;
  const int cx = (i & 15) << 2, ry = i >> 4;
#pragma unroll
  for (int p = 0; p < 4; ++p) {
    int row = ry + p * 16;
    float4 v = *(const float4*)&src[(size_t)(r0 + row) * C + c0 + cx];
    tile[row][cx + 0] = v.x; tile[row][cx + 1] = v.y;
    tile[row][cx + 2] = v.z; tile[row][cx + 3] = v.w;
  }
  __syncthreads();
#pragma unroll
  for (int p = 0; p < 4; ++p) {
    int cr = ry + p * 16;  // output row = source col c0+cr
    ushort4 o;
    o.x = f2bf(tile[cx + 0][cr]); o.y = f2bf(tile[cx + 1][cr]);
    o.z = f2bf(tile[cx + 2][cr]); o.w = f2bf(tile[cx + 3][cr]);
    *(ushort4*)&dst[(size_t)(c0 + cr) * R + r0 + cx] = o;
  }
}

// ---------------- transpose W_x fp32 [2048][32] -> bf16 [32][2048] ----------------
__global__ __launch_bounds__(256)
void txpose_wx(const float* __restrict__ src, u16* __restrict__ dst) {
  const int gid = blockIdx.x * 256 + threadIdx.x;  // 65536
  const int k = gid >> 5, n = gid & 31;
  dst[(size_t)n * DI + k] = f2bf(src[gid]);
}

// ---------------- layernorm fp32 -> bf16 ----------------
__global__ __launch_bounds__(256)
void layernorm_bf16(const float* __restrict__ x, const float* __restrict__ lw,
                    const float* __restrict__ lb, u16* __restrict__ xn) {
  const int row = blockIdx.x, tid = threadIdx.x;
  const float4 v = *(const float4*)&x[(size_t)row * DM + tid * 4];
  float s = v.x + v.y + v.z + v.w;
  float q = v.x * v.x + v.y * v.y + v.z * v.z + v.w * v.w;
#pragma unroll
  for (int m = 1; m < 64; m <<= 1) { s += __shfl_xor(s, m); q += __shfl_xor(q, m); }
  __shared__ float red[8];
  const int w = tid >> 6, lane = tid & 63;
  if (lane == 0) { red[w] = s; red[4 + w] = q; }
  __syncthreads();
  s = red[0] + red[1] + red[2] + red[3];
  q = red[4] + red[5] + red[6] + red[7];
  const float mu = s * (1.f / DM);
  const float var = q * (1.f / DM) - mu * mu;
  const float rs = rsqrtf(var + 1e-5f);
  const float4 wv = *(const float4*)&lw[tid * 4];
  const float4 bv = *(const float4*)&lb[tid * 4];
  ushort4 o;
  o.x = f2bf((v.x - mu) * rs * wv.x + bv.x);
  o.y = f2bf((v.y - mu) * rs * wv.y + bv.y);
  o.z = f2bf((v.z - mu) * rs * wv.z + bv.z);
  o.w = f2bf((v.w - mu) * rs * wv.w + bv.w);
  *(ushort4*)&xn[(size_t)row * DM + tid * 4] = o;
}

// ---------------- 256x256 double-buffered MFMA GEMM (per-wave 128x64) ----------
// BM=256, BN=256, BK=64; 8 waves (2Mx4N); 2-buffer LDS (128 KB), counted vmcnt(8);
// XOR chunk swizzle both sides (rule #21). out bf16 (+bias).
#define TILE256 (2 * 256 * 64)  // u16 per dbuf slot (A 256x64 + B 256x64)
__global__ __launch_bounds__(512, 2)
void gemm_256(const u16* __restrict__ A, const u16* __restrict__ Bt,
              const float* __restrict__ bias, u16* __restrict__ out,
              int M, int N, int K) {
  __shared__ __align__(16) u16 lds[2 * TILE256];  // 128 KB
  const int tid = threadIdx.x, wid = tid >> 6, lane = tid & 63;
  const int ntiles = N >> 8;
  int bid = blockIdx.x;
  {  // XCD-aware swizzle (grid % 8 == 0)
    const int cpx = gridDim.x >> 3;
    bid = (bid & 7) * cpx + (bid >> 3);
  }
  const int tm = bid / ntiles, tn = bid % ntiles;
  const int m0 = tm << 8, n0 = tn << 8;
  const int wm = (wid >> 2) * 128, wn = (wid & 3) * 64;
  const int fr = lane & 15, fg = lane >> 4;
  const int c0 = (fg ^ (fr & 7)) << 4;  // swizzled byte offset of ks0 chunk
  const int NK = K >> 6;

  f32x4 acc[8][4];
#pragma unroll
  for (int mi = 0; mi < 8; ++mi)
#pragma unroll
    for (int ni = 0; ni < 4; ++ni) acc[mi][ni] = (f32x4){0.f, 0.f, 0.f, 0.f};

  auto stage = [&](int T) {
    const int kt = T << 6;
    u16* buf = lds + (T & 1) * TILE256;
#pragma unroll
    for (int i = 0; i < 4; ++i) {  // A: 256 rows x 8 chunks = 2048
      const int s = i * 512 + tid;
      const int row = s >> 3, l = (s & 7) ^ (row & 7);
      g2lds16(A + (size_t)(m0 + row) * K + kt + l * 8, buf + s * 8);
    }
    u16* bufB = buf + 256 * 64;
#pragma unroll
    for (int i = 0; i < 4; ++i) {
      const int s = i * 512 + tid;
      const int row = s >> 3, l = (s & 7) ^ (row & 7);
      g2lds16(Bt + (size_t)(n0 + row) * K + kt + l * 8, bufB + s * 8);
    }
  };

  stage(0); stage(1);                                // 16 loads/thread in flight
  asm volatile("s_waitcnt vmcnt(8)" ::: "memory");   // tile 0 landed
  __builtin_amdgcn_s_barrier();
  asm volatile("" ::: "memory");

  for (int T = 0; T < NK; ++T) {
    const char* bufA = (const char*)(lds + (T & 1) * TILE256);
    const char* bufB = bufA + 256 * 64 * 2;
#pragma unroll
    for (int ks = 0; ks < 2; ++ks) {
      const int cb = c0 ^ (ks << 6);
      bf16x8 af[8], bfr[4];
#pragma unroll
      for (int ni = 0; ni < 4; ++ni)
        bfr[ni] = *(const bf16x8*)(bufB + (wn + ni * 16 + fr) * 128 + cb);
#pragma unroll
      for (int mi = 0; mi < 8; ++mi)
        af[mi] = *(const bf16x8*)(bufA + (wm + mi * 16 + fr) * 128 + cb);
      __builtin_amdgcn_s_setprio(1);
#pragma unroll
      for (int mi = 0; mi < 8; ++mi)
#pragma unroll
        for (int ni = 0; ni < 4; ++ni)
          acc[mi][ni] = __builtin_amdgcn_mfma_f32_16x16x32_bf16(
              af[mi], bfr[ni], acc[mi][ni], 0, 0, 0);
      __builtin_amdgcn_s_setprio(0);
    }
    // frags consumed by MFMA (compiler lgkm-waits) -> buffer free after barrier
    __builtin_amdgcn_s_barrier();
    asm volatile("" ::: "memory");
    if (T + 2 < NK) {
      stage(T + 2);
      asm volatile("s_waitcnt vmcnt(8)" ::: "memory");  // tile T+1 complete
    } else if (T + 1 < NK) {
      asm volatile("s_waitcnt vmcnt(0)" ::: "memory");  // tail: last tile
    }
    __builtin_amdgcn_s_barrier();
    asm volatile("" ::: "memory");
  }

#pragma unroll
  for (int mi = 0; mi < 8; ++mi)
#pragma unroll
    for (int ni = 0; ni < 4; ++ni) {
      const int col = n0 + wn + ni * 16 + fr;
      const float bcol = bias[col];
#pragma unroll
      for (int j = 0; j < 4; ++j) {
        const int row = m0 + wm + mi * 16 + fg * 4 + j;
        out[(size_t)row * N + col] = f2bf(acc[mi][ni][j] + bcol);
      }
    }
}

// ---------------- pipelined bf16 MFMA GEMM (128x256, 3-buffer) ----------------
// Used for GEMM2 (N=1024 -> 256 blocks, full CU coverage).
#define TILE_U16 ((128 + 256) * 64)
template <int EPI>
__global__ __launch_bounds__(512, 1)
void gemm3(const u16* __restrict__ A, const u16* __restrict__ Bt,
           const float* __restrict__ bias, const float* __restrict__ resid,
           void* __restrict__ out, int M, int N, int K) {
  __shared__ __align__(16) u16 lds[3 * TILE_U16];
  const int tid = threadIdx.x, wid = tid >> 6, lane = tid & 63;
  const int ntiles = N >> 8;
  int bid = blockIdx.x;
  {
    const int cpx = gridDim.x >> 3;
    bid = (bid & 7) * cpx + (bid >> 3);
  }
  const int tm = bid / ntiles, tn = bid % ntiles;
  const int m0 = tm << 7, n0 = tn << 8;
  const int wm = (wid >> 2) * 64, wn = (wid & 3) * 64;
  const int fr = lane & 15, fg = lane >> 4;
  const int c0 = (fg ^ (fr & 7)) << 4;
  const int NK = K >> 6;

  f32x4 acc[4][4];
#pragma unroll
  for (int mi = 0; mi < 4; ++mi)
#pragma unroll
    for (int ni = 0; ni < 4; ++ni) acc[mi][ni] = (f32x4){0.f, 0.f, 0.f, 0.f};

  auto stage = [&](int T) {
    const int kt = T << 6;
    u16* buf = lds + (T % 3) * TILE_U16;
#pragma unroll
    for (int i = 0; i < 2; ++i) {
      const int s = i * 512 + tid;
      const int row = s >> 3, l = (s & 7) ^ (row & 7);
      g2lds16(A + (size_t)(m0 + row) * K + kt + l * 8, buf + s * 8);
    }
    u16* bufB = buf + 128 * 64;
#pragma unroll
    for (int i = 0; i < 4; ++i) {
      const int s = i * 512 + tid;
      const int row = s >> 3, l = (s & 7) ^ (row & 7);
      g2lds16(Bt + (size_t)(n0 + row) * K + kt + l * 8, bufB + s * 8);
    }
  };

  stage(0); stage(1); stage(2);
  asm volatile("s_waitcnt vmcnt(12)" ::: "memory");
  __builtin_amdgcn_s_barrier();
  asm volatile("" ::: "memory");

  for (int T = 0; T < NK; ++T) {
    const char* bufA = (const char*)(lds + (T % 3) * TILE_U16);
    const char* bufB = bufA + 128 * 64 * 2;
    bf16x8 af[2][4], bf_[2][4];
#pragma unroll
    for (int ks = 0; ks < 2; ++ks) {
      const int cb = c0 ^ (ks << 6);
#pragma unroll
      for (int mi = 0; mi < 4; ++mi)
        af[ks][mi] = *(const bf16x8*)(bufA + (wm + mi * 16 + fr) * 128 + cb);
#pragma unroll
      for (int ni = 0; ni < 4; ++ni)
        bf_[ks][ni] = *(const bf16x8*)(bufB + (wn + ni * 16 + fr) * 128 + cb);
    }
    __builtin_amdgcn_s_setprio(1);
#pragma unroll
    for (int ks = 0; ks < 2; ++ks)
#pragma unroll
      for (int mi = 0; mi < 4; ++mi)
#pragma unroll
        for (int ni = 0; ni < 4; ++ni)
          acc[mi][ni] = __builtin_amdgcn_mfma_f32_16x16x32_bf16(
              af[ks][mi], bf_[ks][ni], acc[mi][ni], 0, 0, 0);
    __builtin_amdgcn_s_setprio(0);
    __builtin_amdgcn_s_barrier();
    asm volatile("" ::: "memory");
    if (T + 3 < NK) {
      stage(T + 3);
      asm volatile("s_waitcnt vmcnt(12)" ::: "memory");
    } else if (T + 2 < NK) {
      asm volatile("s_waitcnt vmcnt(6)" ::: "memory");
    } else if (T + 1 < NK) {
      asm volatile("s_waitcnt vmcnt(0)" ::: "memory");
    }
    __builtin_amdgcn_s_barrier();
    asm volatile("" ::: "memory");
  }

#pragma unroll
  for (int mi = 0; mi < 4; ++mi)
#pragma unroll
    for (int ni = 0; ni < 4; ++ni) {
      const int col = n0 + wn + ni * 16 + fr;
      const float bcol = bias[col];
#pragma unroll
      for (int j = 0; j < 4; ++j) {
        const int row = m0 + wm + mi * 16 + fg * 4 + j;
        float v = acc[mi][ni][j] + bcol;
        if (EPI == 1) {
          ((float*)out)[(size_t)row * N + col] = v + resid[(size_t)row * N + col];
        } else {
          ((u16*)out)[(size_t)row * N + col] = f2bf(v);
        }
      }
    }
}

// ---------------- causal conv1d + SiLU (elementwise) ----------------
__global__ __launch_bounds__(256)
void conv_silu(const u16* __restrict__ xg, const float* __restrict__ cw,
               const float* __restrict__ cb, u16* __restrict__ xconv) {
  const int t = blockIdx.x;
  const int s = t & (SEQ - 1);
  const int d = threadIdx.x * 8;
  float xv[4][8];
#pragma unroll
  for (int j = 0; j < 4; ++j) {
    const int ss = s - 3 + j;
    if (ss >= 0) {
      uint4 u = *(const uint4*)&xg[(size_t)(t - 3 + j) * (2 * DI) + d];
      const u16* pu = (const u16*)&u;
#pragma unroll
      for (int q = 0; q < 8; ++q) xv[j][q] = bf2f(pu[q]);
    } else {
#pragma unroll
      for (int q = 0; q < 8; ++q) xv[j][q] = 0.f;
    }
  }
  u16 outp[8];
#pragma unroll
  for (int q = 0; q < 8; ++q) {
    const float4 wq = *(const float4*)&cw[(d + q) * 4];
    float a = cb[d + q] + wq.x * xv[0][q] + wq.y * xv[1][q] + wq.z * xv[2][q] +
              wq.w * xv[3][q];
    outp[q] = f2bf(a / (1.f + __expf(-a)));
  }
  *(uint4*)&xconv[(size_t)t * DI + d] = *(const uint4*)outp;
}

// ---------------- BC projection: split-K MFMA GEMM ----------------
__global__ __launch_bounds__(256)
void bc_gemm(const u16* __restrict__ xconv, const u16* __restrict__ wxT,
             float* __restrict__ BCp) {
  __shared__ __align__(16) u16 As[128 * 64];
  __shared__ __align__(16) u16 Bs[32 * 64];
  const int tid = threadIdx.x, w = tid >> 6, lane = tid & 63;
  const int mt = blockIdx.x & 63;
  const int ks_id = blockIdx.x >> 6;
  const int m0 = mt << 7;
  const int k0 = ks_id << 9;
  const int fr = lane & 15, fg = lane >> 4;
  f32x4 acc[2][2];
#pragma unroll
  for (int mf = 0; mf < 2; ++mf)
#pragma unroll
    for (int nf = 0; nf < 2; ++nf) acc[mf][nf] = (f32x4){0.f, 0.f, 0.f, 0.f};

  for (int kt = k0; kt < k0 + 512; kt += 64) {
#pragma unroll
    for (int i = 0; i < 4; ++i) {
      int ch = w * 64 + lane + i * 256;
      int row = ch >> 3, c16 = ch & 7;
      g2lds16(xconv + (size_t)(m0 + row) * DI + kt + c16 * 8,
              (u16*)As + (size_t)(w * 64 + i * 256) * 8);
    }
    {
      int row = tid >> 3, c16 = tid & 7;
      g2lds16(wxT + (size_t)row * DI + kt + c16 * 8,
              (u16*)Bs + (size_t)(w * 64) * 8);
    }
    __syncthreads();
#pragma unroll
    for (int ks = 0; ks < 2; ++ks) {
      bf16x8 af[2], bfr[2];
#pragma unroll
      for (int mf = 0; mf < 2; ++mf)
        af[mf] = *(const bf16x8*)&As[(w * 32 + mf * 16 + fr) * 64 + ks * 32 + fg * 8];
#pragma unroll
      for (int nf = 0; nf < 2; ++nf)
        bfr[nf] = *(const bf16x8*)&Bs[(nf * 16 + fr) * 64 + ks * 32 + fg * 8];
#pragma unroll
      for (int mf = 0; mf < 2; ++mf)
#pragma unroll
        for (int nf = 0; nf < 2; ++nf)
          acc[mf][nf] = __builtin_amdgcn_mfma_f32_16x16x32_bf16(
              af[mf], bfr[nf], acc[mf][nf], 0, 0, 0);
    }
    __syncthreads();
  }
#pragma unroll
  for (int mf = 0; mf < 2; ++mf)
#pragma unroll
    for (int nf = 0; nf < 2; ++nf) {
      const int col = nf * 16 + fr;
#pragma unroll
      for (int j = 0; j < 4; ++j) {
        const int row = m0 + w * 32 + mf * 16 + fg * 4 + j;
        BCp[((size_t)ks_id * TOKENS + row) * 32 + col] = acc[mf][nf][j];
      }
    }
}

// ---------------- reduce split-K partials + bias + B/C interleave ----------------
__global__ __launch_bounds__(256)
void bc_reduce(const float* __restrict__ BCp, const float* __restrict__ bx,
               float* __restrict__ BC) {
  const int gid = blockIdx.x * 256 + threadIdx.x;
  const int c = gid & 31;
  const size_t t = gid >> 5;
  float s = bx[c] + BCp[t * 32 + c] + BCp[((size_t)TOKENS + t) * 32 + c] +
            BCp[((size_t)2 * TOKENS + t) * 32 + c] +
            BCp[((size_t)3 * TOKENS + t) * 32 + c];
  const int dc = (c < 16) ? 2 * c : 2 * (c - 16) + 1;
  BC[t * 32 + dc] = s;
}

// ---------------- chunked selective scan ----------------
__global__ __launch_bounds__(256)
void scan_passA(const u16* __restrict__ xconv, const float* __restrict__ BC,
                const float* __restrict__ A_log, float* __restrict__ F) {
  __shared__ float bcs[CLEN * 32];
  const int blk = blockIdx.x;
  const int j = blk & (NCH - 1);
  const int dg = (blk >> 5) & 7;
  const int b = blk >> 8;
  const int tid = threadIdx.x;
  const int d = dg * 256 + tid;
  const int t0 = j * CLEN;
  {
    const float4* s4 = (const float4*)(BC + (size_t)(b * SEQ + t0) * 32);
    float4* d4 = (float4*)bcs;
#pragma unroll
    for (int i = 0; i < 2; ++i) d4[tid + i * 256] = s4[tid + i * 256];
  }
  float dA[16], h[16];
#pragma unroll
  for (int n = 0; n < 16; ++n) {
    dA[n] = __expf(-__expf(A_log[d * 16 + n]));
    h[n] = 0.f;
  }
  __syncthreads();
  const u16* xcp = xconv + (size_t)(b * SEQ + t0) * DI + d;
  for (int t = 0; t < CLEN; ++t) {
    const float xc = bf2f(*xcp);
    xcp += DI;
#pragma unroll
    for (int n = 0; n < 16; ++n)
      h[n] = fmaf(dA[n], h[n], xc * bcs[t * 32 + 2 * n]);
  }
  float* fp = F + ((size_t)((b * NCH + j) * DI) + d) * 16;
#pragma unroll
  for (int n = 0; n < 16; n += 4) {
    float4 v = {h[n], h[n + 1], h[n + 2], h[n + 3]};
    *(float4*)&fp[n] = v;
  }
}

__global__ __launch_bounds__(256)
void scan_passB(const float* __restrict__ A_log, float* __restrict__ F) {
  const int gid = blockIdx.x * 256 + threadIdx.x;
  const int n = gid & 15;
  const int d = (gid >> 4) & (DI - 1);
  const int b = gid >> 15;
  const float dAL = __expf(-(float)CLEN * __expf(A_log[d * 16 + n]));
  float carry = 0.f;
  const size_t base = ((size_t)(b * NCH) * DI + d) * 16 + n;
  const size_t stride = (size_t)DI * 16;
  for (int j = 0; j < NCH; ++j) {
    const size_t idx = base + (size_t)j * stride;
    const float f = F[idx];
    F[idx] = carry;
    carry = fmaf(dAL, carry, f);
  }
}

__global__ __launch_bounds__(256)
void scan_passC(const u16* __restrict__ xconv, const u16* __restrict__ xg,
                const float* __restrict__ BC, const float* __restrict__ A_log,
                const float* __restrict__ Dv, const float* __restrict__ F,
                u16* __restrict__ yact) {
  __shared__ float bcs[CLEN * 32];
  const int blk = blockIdx.x;
  const int j = blk & (NCH - 1);
  const int dg = (blk >> 5) & 7;
  const int b = blk >> 8;
  const int tid = threadIdx.x;
  const int d = dg * 256 + tid;
  const int t0 = j * CLEN;
  {
    const float4* s4 = (const float4*)(BC + (size_t)(b * SEQ + t0) * 32);
    float4* d4 = (float4*)bcs;
#pragma unroll
    for (int i = 0; i < 2; ++i) d4[tid + i * 256] = s4[tid + i * 256];
  }
  float dA[16], h[16];
  const float* fp = F + ((size_t)((b * NCH + j) * DI) + d) * 16;
#pragma unroll
  for (int n = 0; n < 16; n += 4) {
    float4 v = *(const float4*)&fp[n];
    h[n] = v.x; h[n + 1] = v.y; h[n + 2] = v.z; h[n + 3] = v.w;
  }
#pragma unroll
  for (int n = 0; n < 16; ++n) dA[n] = __expf(-__expf(A_log[d * 16 + n]));
  const float Dd = Dv[d];
  __syncthreads();
  const u16* xcp = xconv + (size_t)(b * SEQ + t0) * DI + d;
  const u16* gp = xg + (size_t)(b * SEQ + t0) * (2 * DI) + DI + d;
  u16* yp = yact + (size_t)(b * SEQ + t0) * DI + d;
  for (int t = 0; t < CLEN; ++t) {
    const float xc = bf2f(*xcp);
    const float g = bf2f(*gp);
    float y0 = 0.f, y1 = 0.f, y2 = 0.f, y3 = 0.f;
#pragma unroll
    for (int n = 0; n < 16; n += 4) {
      h[n]     = fmaf(dA[n],     h[n],     xc * bcs[t * 32 + 2 * n]);
      y0 = fmaf(bcs[t * 32 + 2 * n + 1], h[n], y0);
      h[n + 1] = fmaf(dA[n + 1], h[n + 1], xc * bcs[t * 32 + 2 * n + 2]);
      y1 = fmaf(bcs[t * 32 + 2 * n + 3], h[n + 1], y1);
      h[n + 2] = fmaf(dA[n + 2], h[n + 2], xc * bcs[t * 32 + 2 * n + 4]);
      y2 = fmaf(bcs[t * 32 + 2 * n + 5], h[n + 2], y2);
      h[n + 3] = fmaf(dA[n + 3], h[n + 3], xc * bcs[t * 32 + 2 * n + 6]);
      y3 = fmaf(bcs[t * 32 + 2 * n + 7], h[n + 3], y3);
    }
    const float y = (y0 + y1) + (y2 + y3);
    const float ya = (y + xc * Dd) * (g / (1.f + __expf(-g)));
    *yp = f2bf(ya);
    xcp += DI; gp += 2 * DI; yp += DI;
  }
}

extern "C" void kernel_launch(void* const* d_in, const int* in_sizes, int n_in,
                              void* d_out, int out_size, void* d_ws, size_t ws_size,
                              hipStream_t stream) {
  const float* x     = (const float*)d_in[0];
  const float* ln_w  = (const float*)d_in[1];
  const float* ln_b  = (const float*)d_in[2];
  const float* W_in  = (const float*)d_in[3];
  const float* b_in  = (const float*)d_in[4];
  const float* cw    = (const float*)d_in[5];
  const float* cb    = (const float*)d_in[6];
  const float* A_log = (const float*)d_in[7];
  const float* Dv    = (const float*)d_in[8];
  const float* W_x   = (const float*)d_in[9];
  const float* b_x   = (const float*)d_in[10];
  const float* W_out = (const float*)d_in[11];
  const float* b_out = (const float*)d_in[12];

  char* ws = (char*)d_ws;
  size_t off = 0;
  auto alloc = [&](size_t bytes) {
    void* p = ws + off;
    off += (bytes + 255) & ~(size_t)255;
    return p;
  };
  u16* WinT  = (u16*)alloc((size_t)(2 * DI) * DM * 2);
  u16* WoutT = (u16*)alloc((size_t)DM * DI * 2);
  u16* xn    = (u16*)alloc((size_t)TOKENS * DM * 2);  // reused as F after GEMM1
  u16* xg    = (u16*)alloc((size_t)TOKENS * (2 * DI) * 2);
  u16* xconv = (u16*)alloc((size_t)TOKENS * DI * 2);
  float* BC  = (float*)alloc((size_t)TOKENS * 32 * 4);
  u16* yact  = (u16*)alloc((size_t)TOKENS * DI * 2);
  u16* WxT   = (u16*)alloc((size_t)32 * DI * 2);
  float* BCp = (float*)alloc((size_t)4 * TOKENS * 32 * 4);
  float* F   = (float*)xn;
  (void)ws_size; (void)in_sizes; (void)n_in; (void)out_size;

  transpose_to_bf16<<<(DM / 64) * ((2 * DI) / 64), 256, 0, stream>>>(W_in, WinT, DM, 2 * DI);
  transpose_to_bf16<<<(DI / 64) * (DM / 64), 256, 0, stream>>>(W_out, WoutT, DI, DM);
  txpose_wx<<<(DI * 32) / 256, 256, 0, stream>>>(W_x, WxT);
  layernorm_bf16<<<TOKENS, 256, 0, stream>>>(x, ln_w, ln_b, xn);
  gemm_256<<<(TOKENS / 256) * ((2 * DI) / 256), 512, 0, stream>>>(
      xn, WinT, b_in, xg, TOKENS, 2 * DI, DM);
  conv_silu<<<TOKENS, 256, 0, stream>>>(xg, cw, cb, xconv);
  bc_gemm<<<256, 256, 0, stream>>>(xconv, WxT, BCp);
  bc_reduce<<<(TOKENS * 32) / 256, 256, 0, stream>>>(BCp, b_x, BC);
  scan_passA<<<4 * 8 * NCH, 256, 0, stream>>>(xconv, BC, A_log, F);
  scan_passB<<<512, 256, 0, stream>>>(A_log, F);
  scan_passC<<<4 * 8 * NCH, 256, 0, stream>>>(xconv, xg, BC, A_log, Dv, F, yact);
  gemm3<1><<<(TOKENS / 128) * (DM / 256), 512, 0, stream>>>(
      yact, WoutT, b_out, x, d_out, TOKENS, DM, DI);
}

// Round 8
// 383.186 us; speedup vs baseline: 4.7134x; 1.0288x over previous
//
#include <hip/hip_runtime.h>
#include <stdint.h>

typedef unsigned short u16;
typedef short bf16x8 __attribute__((ext_vector_type(8)));
typedef float f32x4 __attribute__((ext_vector_type(4)));

#define TOKENS 8192
#define SEQ 2048
#define DM 1024
#define DI 2048
#define NCH 32   // time chunks per sequence
#define CLEN 64  // SEQ / NCH

__device__ __forceinline__ float bf2f(u16 u) {
  union { uint32_t i; float f; } v; v.i = ((uint32_t)u) << 16; return v.f;
}
__device__ __forceinline__ u16 f2bf(float f) {
  union { float f; uint32_t i; } v; v.f = f;
  uint32_t r = v.i + 0x7FFFu + ((v.i >> 16) & 1u);
  return (u16)(r >> 16);
}

__device__ __forceinline__ void g2lds16(const void* g, void* l) {
  __builtin_amdgcn_global_load_lds(
      (const __attribute__((address_space(1))) uint32_t*)g,
      (__attribute__((address_space(3))) uint32_t*)l, 16, 0, 0);
}

// ---------------- transpose fp32 [R][C] -> bf16 [C][R] ----------------
__global__ __launch_bounds__(256)
void transpose_to_bf16(const float* __restrict__ src, u16* __restrict__ dst,
                       int R, int C) {
  __shared__ float tile[64][65];
  const int i = threadIdx.x;
  const int tilesC = C >> 6;
  const int br = blockIdx.x / tilesC, bc = blockIdx.x % tilesC;
  const int r0 = br << 6, c0 = bc << 6;
  const int cx = (i & 15) << 2, ry = i >> 4;
#pragma unroll
  for (int p = 0; p < 4; ++p) {
    int row = ry + p * 16;
    float4 v = *(const float4*)&src[(size_t)(r0 + row) * C + c0 + cx];
    tile[row][cx + 0] = v.x; tile[row][cx + 1] = v.y;
    tile[row][cx + 2] = v.z; tile[row][cx + 3] = v.w;
  }
  __syncthreads();
#pragma unroll
  for (int p = 0; p < 4; ++p) {
    int cr = ry + p * 16;  // output row = source col c0+cr
    ushort4 o;
    o.x = f2bf(tile[cx + 0][cr]); o.y = f2bf(tile[cx + 1][cr]);
    o.z = f2bf(tile[cx + 2][cr]); o.w = f2bf(tile[cx + 3][cr]);
    *(ushort4*)&dst[(size_t)(c0 + cr) * R + r0 + cx] = o;
  }
}

// ---------------- transpose W_x fp32 [2048][32] -> bf16 [32][2048] ----------------
__global__ __launch_bounds__(256)
void txpose_wx(const float* __restrict__ src, u16* __restrict__ dst) {
  const int gid = blockIdx.x * 256 + threadIdx.x;  // 65536
  const int k = gid >> 5, n = gid & 31;
  dst[(size_t)n * DI + k] = f2bf(src[gid]);
}

// ---------------- layernorm fp32 -> bf16 ----------------
__global__ __launch_bounds__(256)
void layernorm_bf16(const float* __restrict__ x, const float* __restrict__ lw,
                    const float* __restrict__ lb, u16* __restrict__ xn) {
  const int row = blockIdx.x, tid = threadIdx.x;
  const float4 v = *(const float4*)&x[(size_t)row * DM + tid * 4];
  float s = v.x + v.y + v.z + v.w;
  float q = v.x * v.x + v.y * v.y + v.z * v.z + v.w * v.w;
#pragma unroll
  for (int m = 1; m < 64; m <<= 1) { s += __shfl_xor(s, m); q += __shfl_xor(q, m); }
  __shared__ float red[8];
  const int w = tid >> 6, lane = tid & 63;
  if (lane == 0) { red[w] = s; red[4 + w] = q; }
  __syncthreads();
  s = red[0] + red[1] + red[2] + red[3];
  q = red[4] + red[5] + red[6] + red[7];
  const float mu = s * (1.f / DM);
  const float var = q * (1.f / DM) - mu * mu;
  const float rs = rsqrtf(var + 1e-5f);
  const float4 wv = *(const float4*)&lw[tid * 4];
  const float4 bv = *(const float4*)&lb[tid * 4];
  ushort4 o;
  o.x = f2bf((v.x - mu) * rs * wv.x + bv.x);
  o.y = f2bf((v.y - mu) * rs * wv.y + bv.y);
  o.z = f2bf((v.z - mu) * rs * wv.z + bv.z);
  o.w = f2bf((v.w - mu) * rs * wv.w + bv.w);
  *(ushort4*)&xn[(size_t)row * DM + tid * 4] = o;
}

// ---------------- 8-phase 256x256 MFMA GEMM (per-wave 128x64) ----------------
// BM=BN=256, BK=64; 8 waves (2Mx4N); 2-buffer LDS (128 KB); 4 quadrant-phases
// per K-tile; counted vmcnt(6) once per K-tile (never 0 in steady state).
// Stage ledger per tile t phase q (unit = 64 rows = one g2lds across 512 thr):
//   q0: A1,A3 of t+1   (regions freed after (t-1,3))
//   q1: B0,B1 of t+2   (B of buf[t&1] freed after (t,0))
//   q2: B2,B3 of t+2
//   q3: A0,A2 of t+2   (A rows 0-63/128-191 freed after (t,1))
// vmcnt(6)@q3 => everything except q1..q3's 6 loads landed => tile t+1 ready.
// LDS slot layout (bytes): A [0,32768), B [32768,65536).
#define TILE256 (2 * 256 * 64)  // u16 per dbuf slot (A 256x64 + B 256x64)
__global__ __launch_bounds__(512, 2)
void gemm8(const u16* __restrict__ A, const u16* __restrict__ Bt,
           const float* __restrict__ bias, u16* __restrict__ out,
           int M, int N, int K) {
  __shared__ __align__(16) u16 lds[2 * TILE256];  // 128 KB
  const int tid = threadIdx.x, wid = tid >> 6, lane = tid & 63;
  const int ntiles = N >> 8;
  int bid = blockIdx.x;
  {  // XCD-aware swizzle (grid % 8 == 0)
    const int cpx = gridDim.x >> 3;
    bid = (bid & 7) * cpx + (bid >> 3);
  }
  const int tm = bid / ntiles, tn = bid % ntiles;
  const int m0 = tm << 8, n0 = tn << 8;
  const int wm = (wid >> 2) * 128, wn = (wid & 3) * 64;
  const int fr = lane & 15, fg = lane >> 4;
  const int c0 = (fg ^ (fr & 7)) << 4;  // swizzled byte offset of ks0 chunk
  const int NK = K >> 6;

  f32x4 acc[8][4];
#pragma unroll
  for (int mi = 0; mi < 8; ++mi)
#pragma unroll
    for (int ni = 0; ni < 4; ++ni) acc[mi][ni] = (f32x4){0.f, 0.f, 0.f, 0.f};

  // stage one 64-row unit (8 KB) of tile T, matrix isB, unit u
  auto stage_unit = [&](int T, int isB, int u) {
    const int kt = T << 6;
    const int row = u * 64 + (tid >> 3);
    const int l = (tid & 7) ^ (row & 7);
    const u16* src = (isB ? Bt + (size_t)(n0 + row) * K
                          : A + (size_t)(m0 + row) * K) + kt + l * 8;
    g2lds16(src, lds + (size_t)(T & 1) * TILE256 + isB * 16384 + u * 4096 + tid * 8);
  };

  // prologue: tile0 full (8), tile1 B0-3 + A0,A2 (6) -> vmcnt(6) = tile0 landed
#pragma unroll
  for (int u = 0; u < 4; ++u) stage_unit(0, 1, u);
#pragma unroll
  for (int u = 0; u < 4; ++u) stage_unit(0, 0, u);
#pragma unroll
  for (int u = 0; u < 4; ++u) stage_unit(1, 1, u);
  stage_unit(1, 0, 0); stage_unit(1, 0, 2);
  asm volatile("s_waitcnt vmcnt(6)" ::: "memory");
  __builtin_amdgcn_s_barrier();
  asm volatile("" ::: "memory");

  bf16x8 bfr[2][4];
  for (int t = 0; t < NK; ++t) {
    const char* bufA = (const char*)(lds + (t & 1) * TILE256);
    const char* bufB = bufA + 32768;  // A region is 256*64*2 = 32768 bytes
#pragma unroll
    for (int q = 0; q < 4; ++q) {
      // ---- ds_read register subtile ----
      bf16x8 af[2][2];
      if (q == 0) {
#pragma unroll
        for (int ks = 0; ks < 2; ++ks) {
          const int cb = c0 ^ (ks << 6);
#pragma unroll
          for (int ni = 0; ni < 4; ++ni)
            bfr[ks][ni] = *(const bf16x8*)(bufB + (wn + ni * 16 + fr) * 128 + cb);
        }
      }
#pragma unroll
      for (int ks = 0; ks < 2; ++ks) {
        const int cb = c0 ^ (ks << 6);
#pragma unroll
        for (int r = 0; r < 2; ++r)
          af[ks][r] = *(const bf16x8*)(bufA + (wm + (2 * q + r) * 16 + fr) * 128 + cb);
      }
      // ---- stage per ledger ----
      if (q == 0) {
        if (t + 1 < NK) { stage_unit(t + 1, 0, 1); stage_unit(t + 1, 0, 3); }
      } else if (q == 1) {
        if (t + 2 < NK) { stage_unit(t + 2, 1, 0); stage_unit(t + 2, 1, 1); }
      } else if (q == 2) {
        if (t + 2 < NK) { stage_unit(t + 2, 1, 2); stage_unit(t + 2, 1, 3); }
      } else {
        if (t + 2 < NK) { stage_unit(t + 2, 0, 0); stage_unit(t + 2, 0, 2); }
      }
      __builtin_amdgcn_sched_barrier(0);
      __builtin_amdgcn_s_barrier();
      asm volatile("s_waitcnt lgkmcnt(0)" ::: "memory");
      __builtin_amdgcn_sched_barrier(0);
      __builtin_amdgcn_s_setprio(1);
#pragma unroll
      for (int ks = 0; ks < 2; ++ks)
#pragma unroll
        for (int r = 0; r < 2; ++r)
#pragma unroll
          for (int ni = 0; ni < 4; ++ni)
            acc[2 * q + r][ni] = __builtin_amdgcn_mfma_f32_16x16x32_bf16(
                af[ks][r], bfr[ks][ni], acc[2 * q + r][ni], 0, 0, 0);
      __builtin_amdgcn_s_setprio(0);
      if (q == 3) {
        if (t + 2 < NK) {
          asm volatile("s_waitcnt vmcnt(6)" ::: "memory");
        } else if (t + 1 < NK) {
          asm volatile("s_waitcnt vmcnt(0)" ::: "memory");
        }
      }
      __builtin_amdgcn_s_barrier();
      asm volatile("" ::: "memory");
    }
  }

#pragma unroll
  for (int mi = 0; mi < 8; ++mi)
#pragma unroll
    for (int ni = 0; ni < 4; ++ni) {
      const int col = n0 + wn + ni * 16 + fr;
      const float bcol = bias[col];
#pragma unroll
      for (int j = 0; j < 4; ++j) {
        const int row = m0 + wm + mi * 16 + fg * 4 + j;
        out[(size_t)row * N + col] = f2bf(acc[mi][ni][j] + bcol);
      }
    }
}

// ---------------- pipelined bf16 MFMA GEMM (128x256, 3-buffer) ----------------
// Used for GEMM2 (N=1024 -> 256 blocks, full CU coverage).
#define TILE_U16 ((128 + 256) * 64)
template <int EPI>
__global__ __launch_bounds__(512, 1)
void gemm3(const u16* __restrict__ A, const u16* __restrict__ Bt,
           const float* __restrict__ bias, const float* __restrict__ resid,
           void* __restrict__ out, int M, int N, int K) {
  __shared__ __align__(16) u16 lds[3 * TILE_U16];
  const int tid = threadIdx.x, wid = tid >> 6, lane = tid & 63;
  const int ntiles = N >> 8;
  int bid = blockIdx.x;
  {
    const int cpx = gridDim.x >> 3;
    bid = (bid & 7) * cpx + (bid >> 3);
  }
  const int tm = bid / ntiles, tn = bid % ntiles;
  const int m0 = tm << 7, n0 = tn << 8;
  const int wm = (wid >> 2) * 64, wn = (wid & 3) * 64;
  const int fr = lane & 15, fg = lane >> 4;
  const int c0 = (fg ^ (fr & 7)) << 4;
  const int NK = K >> 6;

  f32x4 acc[4][4];
#pragma unroll
  for (int mi = 0; mi < 4; ++mi)
#pragma unroll
    for (int ni = 0; ni < 4; ++ni) acc[mi][ni] = (f32x4){0.f, 0.f, 0.f, 0.f};

  auto stage = [&](int T) {
    const int kt = T << 6;
    u16* buf = lds + (T % 3) * TILE_U16;
#pragma unroll
    for (int i = 0; i < 2; ++i) {
      const int s = i * 512 + tid;
      const int row = s >> 3, l = (s & 7) ^ (row & 7);
      g2lds16(A + (size_t)(m0 + row) * K + kt + l * 8, buf + s * 8);
    }
    u16* bufB = buf + 128 * 64;
#pragma unroll
    for (int i = 0; i < 4; ++i) {
      const int s = i * 512 + tid;
      const int row = s >> 3, l = (s & 7) ^ (row & 7);
      g2lds16(Bt + (size_t)(n0 + row) * K + kt + l * 8, bufB + s * 8);
    }
  };

  stage(0); stage(1); stage(2);
  asm volatile("s_waitcnt vmcnt(12)" ::: "memory");
  __builtin_amdgcn_s_barrier();
  asm volatile("" ::: "memory");

  for (int T = 0; T < NK; ++T) {
    const char* bufA = (const char*)(lds + (T % 3) * TILE_U16);
    const char* bufB = bufA + 128 * 64 * 2;
    bf16x8 af[2][4], bf_[2][4];
#pragma unroll
    for (int ks = 0; ks < 2; ++ks) {
      const int cb = c0 ^ (ks << 6);
#pragma unroll
      for (int mi = 0; mi < 4; ++mi)
        af[ks][mi] = *(const bf16x8*)(bufA + (wm + mi * 16 + fr) * 128 + cb);
#pragma unroll
      for (int ni = 0; ni < 4; ++ni)
        bf_[ks][ni] = *(const bf16x8*)(bufB + (wn + ni * 16 + fr) * 128 + cb);
    }
    __builtin_amdgcn_s_setprio(1);
#pragma unroll
    for (int ks = 0; ks < 2; ++ks)
#pragma unroll
      for (int mi = 0; mi < 4; ++mi)
#pragma unroll
        for (int ni = 0; ni < 4; ++ni)
          acc[mi][ni] = __builtin_amdgcn_mfma_f32_16x16x32_bf16(
              af[ks][mi], bf_[ks][ni], acc[mi][ni], 0, 0, 0);
    __builtin_amdgcn_s_setprio(0);
    __builtin_amdgcn_s_barrier();
    asm volatile("" ::: "memory");
    if (T + 3 < NK) {
      stage(T + 3);
      asm volatile("s_waitcnt vmcnt(12)" ::: "memory");
    } else if (T + 2 < NK) {
      asm volatile("s_waitcnt vmcnt(6)" ::: "memory");
    } else if (T + 1 < NK) {
      asm volatile("s_waitcnt vmcnt(0)" ::: "memory");
    }
    __builtin_amdgcn_s_barrier();
    asm volatile("" ::: "memory");
  }

#pragma unroll
  for (int mi = 0; mi < 4; ++mi)
#pragma unroll
    for (int ni = 0; ni < 4; ++ni) {
      const int col = n0 + wn + ni * 16 + fr;
      const float bcol = bias[col];
#pragma unroll
      for (int j = 0; j < 4; ++j) {
        const int row = m0 + wm + mi * 16 + fg * 4 + j;
        float v = acc[mi][ni][j] + bcol;
        if (EPI == 1) {
          ((float*)out)[(size_t)row * N + col] = v + resid[(size_t)row * N + col];
        } else {
          ((u16*)out)[(size_t)row * N + col] = f2bf(v);
        }
      }
    }
}

// ---------------- causal conv1d + SiLU (elementwise) ----------------
__global__ __launch_bounds__(256)
void conv_silu(const u16* __restrict__ xg, const float* __restrict__ cw,
               const float* __restrict__ cb, u16* __restrict__ xconv) {
  const int t = blockIdx.x;
  const int s = t & (SEQ - 1);
  const int d = threadIdx.x * 8;
  float xv[4][8];
#pragma unroll
  for (int j = 0; j < 4; ++j) {
    const int ss = s - 3 + j;
    if (ss >= 0) {
      uint4 u = *(const uint4*)&xg[(size_t)(t - 3 + j) * (2 * DI) + d];
      const u16* pu = (const u16*)&u;
#pragma unroll
      for (int q = 0; q < 8; ++q) xv[j][q] = bf2f(pu[q]);
    } else {
#pragma unroll
      for (int q = 0; q < 8; ++q) xv[j][q] = 0.f;
    }
  }
  u16 outp[8];
#pragma unroll
  for (int q = 0; q < 8; ++q) {
    const float4 wq = *(const float4*)&cw[(d + q) * 4];
    float a = cb[d + q] + wq.x * xv[0][q] + wq.y * xv[1][q] + wq.z * xv[2][q] +
              wq.w * xv[3][q];
    outp[q] = f2bf(a / (1.f + __expf(-a)));
  }
  *(uint4*)&xconv[(size_t)t * DI + d] = *(const uint4*)outp;
}

// ---------------- BC projection: split-K MFMA GEMM ----------------
__global__ __launch_bounds__(256)
void bc_gemm(const u16* __restrict__ xconv, const u16* __restrict__ wxT,
             float* __restrict__ BCp) {
  __shared__ __align__(16) u16 As[128 * 64];
  __shared__ __align__(16) u16 Bs[32 * 64];
  const int tid = threadIdx.x, w = tid >> 6, lane = tid & 63;
  const int mt = blockIdx.x & 63;
  const int ks_id = blockIdx.x >> 6;
  const int m0 = mt << 7;
  const int k0 = ks_id << 9;
  const int fr = lane & 15, fg = lane >> 4;
  f32x4 acc[2][2];
#pragma unroll
  for (int mf = 0; mf < 2; ++mf)
#pragma unroll
    for (int nf = 0; nf < 2; ++nf) acc[mf][nf] = (f32x4){0.f, 0.f, 0.f, 0.f};

  for (int kt = k0; kt < k0 + 512; kt += 64) {
#pragma unroll
    for (int i = 0; i < 4; ++i) {
      int ch = w * 64 + lane + i * 256;
      int row = ch >> 3, c16 = ch & 7;
      g2lds16(xconv + (size_t)(m0 + row) * DI + kt + c16 * 8,
              (u16*)As + (size_t)(w * 64 + i * 256) * 8);
    }
    {
      int row = tid >> 3, c16 = tid & 7;
      g2lds16(wxT + (size_t)row * DI + kt + c16 * 8,
              (u16*)Bs + (size_t)(w * 64) * 8);
    }
    __syncthreads();
#pragma unroll
    for (int ks = 0; ks < 2; ++ks) {
      bf16x8 af[2], bfr[2];
#pragma unroll
      for (int mf = 0; mf < 2; ++mf)
        af[mf] = *(const bf16x8*)&As[(w * 32 + mf * 16 + fr) * 64 + ks * 32 + fg * 8];
#pragma unroll
      for (int nf = 0; nf < 2; ++nf)
        bfr[nf] = *(const bf16x8*)&Bs[(nf * 16 + fr) * 64 + ks * 32 + fg * 8];
#pragma unroll
      for (int mf = 0; mf < 2; ++mf)
#pragma unroll
        for (int nf = 0; nf < 2; ++nf)
          acc[mf][nf] = __builtin_amdgcn_mfma_f32_16x16x32_bf16(
              af[mf], bfr[nf], acc[mf][nf], 0, 0, 0);
    }
    __syncthreads();
  }
#pragma unroll
  for (int mf = 0; mf < 2; ++mf)
#pragma unroll
    for (int nf = 0; nf < 2; ++nf) {
      const int col = nf * 16 + fr;
#pragma unroll
      for (int j = 0; j < 4; ++j) {
        const int row = m0 + w * 32 + mf * 16 + fg * 4 + j;
        BCp[((size_t)ks_id * TOKENS + row) * 32 + col] = acc[mf][nf][j];
      }
    }
}

// ---------------- reduce split-K partials + bias (plane layout) --------------
// BC[t][0..16) = B-plane, BC[t][16..32) = C-plane (natural W_x column order)
__global__ __launch_bounds__(256)
void bc_reduce(const float* __restrict__ BCp, const float* __restrict__ bx,
               float* __restrict__ BC) {
  const int gid = blockIdx.x * 256 + threadIdx.x;
  const int c = gid & 31;
  const size_t t = gid >> 5;
  float s = bx[c] + BCp[t * 32 + c] + BCp[((size_t)TOKENS + t) * 32 + c] +
            BCp[((size_t)2 * TOKENS + t) * 32 + c] +
            BCp[((size_t)3 * TOKENS + t) * 32 + c];
  BC[t * 32 + c] = s;
}

// ---------------- chunked selective scan ----------------
__global__ __launch_bounds__(256)
void scan_passA(const u16* __restrict__ xconv, const float* __restrict__ BC,
                const float* __restrict__ A_log, float* __restrict__ F) {
  __shared__ float bcs[CLEN * 32];
  const int blk = blockIdx.x;
  const int j = blk & (NCH - 1);
  const int dg = (blk >> 5) & 7;
  const int b = blk >> 8;
  const int tid = threadIdx.x;
  const int d = dg * 256 + tid;
  const int t0 = j * CLEN;
  {
    const float4* s4 = (const float4*)(BC + (size_t)(b * SEQ + t0) * 32);
    float4* d4 = (float4*)bcs;
#pragma unroll
    for (int i = 0; i < 2; ++i) d4[tid + i * 256] = s4[tid + i * 256];
  }
  float dA[16], h[16];
#pragma unroll
  for (int n = 0; n < 16; ++n) {
    dA[n] = __expf(-__expf(A_log[d * 16 + n]));
    h[n] = 0.f;
  }
  __syncthreads();
  const u16* xcp = xconv + (size_t)(b * SEQ + t0) * DI + d;
  for (int t = 0; t < CLEN; ++t) {
    const float xc = bf2f(*xcp);
    xcp += DI;
    const float* bt = &bcs[t * 32];
#pragma unroll
    for (int n4 = 0; n4 < 4; ++n4) {
      const float4 bv = *(const float4*)&bt[n4 * 4];
      h[4 * n4 + 0] = fmaf(dA[4 * n4 + 0], h[4 * n4 + 0], xc * bv.x);
      h[4 * n4 + 1] = fmaf(dA[4 * n4 + 1], h[4 * n4 + 1], xc * bv.y);
      h[4 * n4 + 2] = fmaf(dA[4 * n4 + 2], h[4 * n4 + 2], xc * bv.z);
      h[4 * n4 + 3] = fmaf(dA[4 * n4 + 3], h[4 * n4 + 3], xc * bv.w);
    }
  }
  float* fp = F + ((size_t)((b * NCH + j) * DI) + d) * 16;
#pragma unroll
  for (int n = 0; n < 16; n += 4) {
    float4 v = {h[n], h[n + 1], h[n + 2], h[n + 3]};
    *(float4*)&fp[n] = v;
  }
}

__global__ __launch_bounds__(256)
void scan_passB(const float* __restrict__ A_log, float* __restrict__ F) {
  const int gid = blockIdx.x * 256 + threadIdx.x;
  const int n = gid & 15;
  const int d = (gid >> 4) & (DI - 1);
  const int b = gid >> 15;
  const float dAL = __expf(-(float)CLEN * __expf(A_log[d * 16 + n]));
  float carry = 0.f;
  const size_t base = ((size_t)(b * NCH) * DI + d) * 16 + n;
  const size_t stride = (size_t)DI * 16;
  for (int j = 0; j < NCH; ++j) {
    const size_t idx = base + (size_t)j * stride;
    const float f = F[idx];
    F[idx] = carry;
    carry = fmaf(dAL, carry, f);
  }
}

__global__ __launch_bounds__(256)
void scan_passC(const u16* __restrict__ xconv, const u16* __restrict__ xg,
                const float* __restrict__ BC, const float* __restrict__ A_log,
                const float* __restrict__ Dv, const float* __restrict__ F,
                u16* __restrict__ yact) {
  __shared__ float bcs[CLEN * 32];
  const int blk = blockIdx.x;
  const int j = blk & (NCH - 1);
  const int dg = (blk >> 5) & 7;
  const int b = blk >> 8;
  const int tid = threadIdx.x;
  const int d = dg * 256 + tid;
  const int t0 = j * CLEN;
  {
    const float4* s4 = (const float4*)(BC + (size_t)(b * SEQ + t0) * 32);
    float4* d4 = (float4*)bcs;
#pragma unroll
    for (int i = 0; i < 2; ++i) d4[tid + i * 256] = s4[tid + i * 256];
  }
  float dA[16], h[16];
  const float* fp = F + ((size_t)((b * NCH + j) * DI) + d) * 16;
#pragma unroll
  for (int n = 0; n < 16; n += 4) {
    float4 v = *(const float4*)&fp[n];
    h[n] = v.x; h[n + 1] = v.y; h[n + 2] = v.z; h[n + 3] = v.w;
  }
#pragma unroll
  for (int n = 0; n < 16; ++n) dA[n] = __expf(-__expf(A_log[d * 16 + n]));
  const float Dd = Dv[d];
  __syncthreads();
  const u16* xcp = xconv + (size_t)(b * SEQ + t0) * DI + d;
  const u16* gp = xg + (size_t)(b * SEQ + t0) * (2 * DI) + DI + d;
  u16* yp = yact + (size_t)(b * SEQ + t0) * DI + d;
  for (int t = 0; t < CLEN; ++t) {
    const float xc = bf2f(*xcp);
    const float g = bf2f(*gp);
    const float* bt = &bcs[t * 32];
    float y0 = 0.f, y1 = 0.f, y2 = 0.f, y3 = 0.f;
#pragma unroll
    for (int n4 = 0; n4 < 4; ++n4) {
      const float4 bv = *(const float4*)&bt[n4 * 4];
      const float4 cv = *(const float4*)&bt[16 + n4 * 4];
      const int n = 4 * n4;
      h[n]     = fmaf(dA[n],     h[n],     xc * bv.x);
      y0 = fmaf(cv.x, h[n], y0);
      h[n + 1] = fmaf(dA[n + 1], h[n + 1], xc * bv.y);
      y1 = fmaf(cv.y, h[n + 1], y1);
      h[n + 2] = fmaf(dA[n + 2], h[n + 2], xc * bv.z);
      y2 = fmaf(cv.z, h[n + 2], y2);
      h[n + 3] = fmaf(dA[n + 3], h[n + 3], xc * bv.w);
      y3 = fmaf(cv.w, h[n + 3], y3);
    }
    const float y = (y0 + y1) + (y2 + y3);
    const float ya = (y + xc * Dd) * (g / (1.f + __expf(-g)));
    *yp = f2bf(ya);
    xcp += DI; gp += 2 * DI; yp += DI;
  }
}

extern "C" void kernel_launch(void* const* d_in, const int* in_sizes, int n_in,
                              void* d_out, int out_size, void* d_ws, size_t ws_size,
                              hipStream_t stream) {
  const float* x     = (const float*)d_in[0];
  const float* ln_w  = (const float*)d_in[1];
  const float* ln_b  = (const float*)d_in[2];
  const float* W_in  = (const float*)d_in[3];
  const float* b_in  = (const float*)d_in[4];
  const float* cw    = (const float*)d_in[5];
  const float* cb    = (const float*)d_in[6];
  const float* A_log = (const float*)d_in[7];
  const float* Dv    = (const float*)d_in[8];
  const float* W_x   = (const float*)d_in[9];
  const float* b_x   = (const float*)d_in[10];
  const float* W_out = (const float*)d_in[11];
  const float* b_out = (const float*)d_in[12];

  char* ws = (char*)d_ws;
  size_t off = 0;
  auto alloc = [&](size_t bytes) {
    void* p = ws + off;
    off += (bytes + 255) & ~(size_t)255;
    return p;
  };
  u16* WinT  = (u16*)alloc((size_t)(2 * DI) * DM * 2);
  u16* WoutT = (u16*)alloc((size_t)DM * DI * 2);
  u16* xn    = (u16*)alloc((size_t)TOKENS * DM * 2);  // reused as F after GEMM1
  u16* xg    = (u16*)alloc((size_t)TOKENS * (2 * DI) * 2);
  u16* xconv = (u16*)alloc((size_t)TOKENS * DI * 2);
  float* BC  = (float*)alloc((size_t)TOKENS * 32 * 4);
  u16* yact  = (u16*)alloc((size_t)TOKENS * DI * 2);
  u16* WxT   = (u16*)alloc((size_t)32 * DI * 2);
  float* BCp = (float*)alloc((size_t)4 * TOKENS * 32 * 4);
  float* F   = (float*)xn;
  (void)ws_size; (void)in_sizes; (void)n_in; (void)out_size;

  transpose_to_bf16<<<(DM / 64) * ((2 * DI) / 64), 256, 0, stream>>>(W_in, WinT, DM, 2 * DI);
  transpose_to_bf16<<<(DI / 64) * (DM / 64), 256, 0, stream>>>(W_out, WoutT, DI, DM);
  txpose_wx<<<(DI * 32) / 256, 256, 0, stream>>>(W_x, WxT);
  layernorm_bf16<<<TOKENS, 256, 0, stream>>>(x, ln_w, ln_b, xn);
  gemm8<<<(TOKENS / 256) * ((2 * DI) / 256), 512, 0, stream>>>(
      xn, WinT, b_in, xg, TOKENS, 2 * DI, DM);
  conv_silu<<<TOKENS, 256, 0, stream>>>(xg, cw, cb, xconv);
  bc_gemm<<<256, 256, 0, stream>>>(xconv, WxT, BCp);
  bc_reduce<<<(TOKENS * 32) / 256, 256, 0, stream>>>(BCp, b_x, BC);
  scan_passA<<<4 * 8 * NCH, 256, 0, stream>>>(xconv, BC, A_log, F);
  scan_passB<<<512, 256, 0, stream>>>(A_log, F);
  scan_passC<<<4 * 8 * NCH, 256, 0, stream>>>(xconv, xg, BC, A_log, Dv, F, yact);
  gemm3<1><<<(TOKENS / 128) * (DM / 256), 512, 0, stream>>>(
      yact, WoutT, b_out, x, d_out, TOKENS, DM, DI);
}